// Round 1
// baseline (503.380 us; speedup 1.0000x reference)
//
#include <hip/hip_runtime.h>
#include <cstdint>
#include <cstddef>

typedef unsigned short u16;
typedef __attribute__((ext_vector_type(8))) __bf16 bf16x8;
typedef __attribute__((ext_vector_type(8))) u16   u16x8;
typedef __attribute__((ext_vector_type(4))) float f32x4;

#define D_MODEL 1024
#define D_INNER 2048
#define NSTATE  16
#define DT_RANK 64
#define BATCH   2
#define SEQ     2048
#define NTOK    (BATCH*SEQ)      // 4096
#define CHUNK   64
#define NCH     (SEQ/CHUNK)      // 32
#define LOG2E   1.44269504088896340736f

static __device__ __forceinline__ u16 f2bf(float f) {
    uint32_t u = __builtin_bit_cast(uint32_t, f);
    u += 0x7fffu + ((u >> 16) & 1u);          // RNE
    return (u16)(u >> 16);
}
static __device__ __forceinline__ float bf2f(u16 h) {
    uint32_t u = ((uint32_t)h) << 16;
    return __builtin_bit_cast(float, u);
}

// ---------------- cast f32 -> bf16 ----------------
__global__ __launch_bounds__(256) void castf2bf(const float* __restrict__ in,
                                                u16* __restrict__ out, int n) {
    int i = blockIdx.x * 256 + threadIdx.x;
    int stride = gridDim.x * 256;
    for (; i < n; i += stride) out[i] = f2bf(in[i]);
}

// ---------------- LayerNorm + bf16 cast ----------------
__global__ __launch_bounds__(256) void ln_cast(const float* __restrict__ x,
                                               const float* __restrict__ w,
                                               const float* __restrict__ bb,
                                               u16* __restrict__ y) {
    int row = blockIdx.x;
    const float4 v = ((const float4*)(x + (size_t)row * D_MODEL))[threadIdx.x];
    float s  = v.x + v.y + v.z + v.w;
    float sq = v.x*v.x + v.y*v.y + v.z*v.z + v.w*v.w;
    #pragma unroll
    for (int o = 32; o > 0; o >>= 1) {
        s  += __shfl_down(s,  o, 64);
        sq += __shfl_down(sq, o, 64);
    }
    __shared__ float sh[8];
    int wv = threadIdx.x >> 6;
    if ((threadIdx.x & 63) == 0) { sh[wv] = s; sh[4 + wv] = sq; }
    __syncthreads();
    s  = sh[0] + sh[1] + sh[2] + sh[3];
    sq = sh[4] + sh[5] + sh[6] + sh[7];
    float mu  = s * (1.f / D_MODEL);
    float var = sq * (1.f / D_MODEL) - mu * mu;
    float inv = rsqrtf(var + 1e-5f);
    int c = threadIdx.x * 4;
    ushort4 o4;
    o4.x = f2bf((v.x - mu) * inv * w[c+0] + bb[c+0]);
    o4.y = f2bf((v.y - mu) * inv * w[c+1] + bb[c+1]);
    o4.z = f2bf((v.z - mu) * inv * w[c+2] + bb[c+2]);
    o4.w = f2bf((v.w - mu) * inv * w[c+3] + bb[c+3]);
    ((ushort4*)(y + (size_t)row * D_MODEL))[threadIdx.x] = o4;
}

// ---------------- generic bf16 MFMA GEMM: C[M,N] = A[M,K] * B[N,K]^T ----------------
// EPI 0: split u/z (N=4096): col<2048 -> u_bf ; col>=2048 -> silu -> zs_bf
// EPI 1: x_proj (N=96): fp32 xdbl[row*96+col] (col<96), bf16 dtin (col<64)
// EPI 2: dt:  softplus(acc + e0[col]) -> fo0[row*N+col]
// EPI 3: out: fo0[row*N+col] = acc + e0[row*N+col]
template<int EPI>
__global__ __launch_bounds__(256) void gemm_bf16(
    const u16* __restrict__ A, const u16* __restrict__ B,
    int M, int N, int K,
    float* __restrict__ fo0, u16* __restrict__ bo0, u16* __restrict__ bo1,
    const float* __restrict__ e0)
{
    __shared__ u16 As[128][64];
    __shared__ u16 Bs[128][64];
    int tid  = threadIdx.x;
    int bm   = blockIdx.y * 128;
    int bn   = blockIdx.x * 128;
    int wid  = tid >> 6, lane = tid & 63;
    int wm   = (wid >> 1) * 64, wn = (wid & 1) * 64;
    int lr   = lane & 15;
    int lk   = (lane >> 4) * 8;

    f32x4 acc[4][4];
    #pragma unroll
    for (int m = 0; m < 4; ++m)
        #pragma unroll
        for (int n = 0; n < 4; ++n)
            #pragma unroll
            for (int r = 0; r < 4; ++r) acc[m][n][r] = 0.f;

    for (int k0 = 0; k0 < K; k0 += 64) {
        #pragma unroll
        for (int i = 0; i < 4; ++i) {
            int c   = i * 256 + tid;
            int row = c >> 3;
            int kc  = (c & 7) * 8;
            // A tile (M always multiple of 128 here)
            u16x8 va = *(const u16x8*)&A[(size_t)(bm + row) * K + k0 + kc];
            *(u16x8*)&As[row][kc] = va;
            // B tile with N guard
            int rg = bn + row;
            u16x8 vb;
            #pragma unroll
            for (int j = 0; j < 8; ++j) vb[j] = 0;
            if (rg < N) vb = *(const u16x8*)&B[(size_t)rg * K + k0 + kc];
            *(u16x8*)&Bs[row][kc] = vb;
        }
        __syncthreads();
        #pragma unroll
        for (int ks = 0; ks < 2; ++ks) {
            bf16x8 af[4], bfr[4];
            #pragma unroll
            for (int m = 0; m < 4; ++m)
                af[m] = *(const bf16x8*)&As[wm + m*16 + lr][ks*32 + lk];
            #pragma unroll
            for (int n = 0; n < 4; ++n)
                bfr[n] = *(const bf16x8*)&Bs[wn + n*16 + lr][ks*32 + lk];
            #pragma unroll
            for (int m = 0; m < 4; ++m)
                #pragma unroll
                for (int n = 0; n < 4; ++n)
                    acc[m][n] = __builtin_amdgcn_mfma_f32_16x16x32_bf16(af[m], bfr[n], acc[m][n], 0, 0, 0);
        }
        __syncthreads();
    }

    int cr0 = (lane >> 4) * 4;
    int cc  = lane & 15;
    #pragma unroll
    for (int m = 0; m < 4; ++m) {
        #pragma unroll
        for (int n = 0; n < 4; ++n) {
            #pragma unroll
            for (int r = 0; r < 4; ++r) {
                int row = bm + wm + m*16 + cr0 + r;
                int col = bn + wn + n*16 + cc;
                float v = acc[m][n][r];
                if (EPI == 0) {
                    if (col < D_INNER) {
                        bo0[(size_t)row * D_INNER + col] = f2bf(v);
                    } else {
                        float s = v / (1.f + __expf(-v));
                        bo1[(size_t)row * D_INNER + (col - D_INNER)] = f2bf(s);
                    }
                } else if (EPI == 1) {
                    if (col < 96) fo0[(size_t)row * 96 + col] = v;
                    if (col < 64) bo0[(size_t)row * 64 + col] = f2bf(v);
                } else if (EPI == 2) {
                    float t = v + e0[col];
                    float sp = (t > 20.f) ? t : log1pf(__expf(t));
                    fo0[(size_t)row * N + col] = sp;
                } else { // EPI == 3
                    fo0[(size_t)row * N + col] = v + e0[(size_t)row * N + col];
                }
            }
        }
    }
}

// ---------------- depthwise causal conv(4) + bias + silu ----------------
__global__ __launch_bounds__(256) void conv_silu(const u16* __restrict__ u,
                                                 const float* __restrict__ cw,
                                                 const float* __restrict__ cb,
                                                 u16* __restrict__ uc) {
    int d   = blockIdx.x * 256 + threadIdx.x;   // 0..2047
    int tok = blockIdx.y;                        // 0..4095
    int t   = tok & (SEQ - 1);
    float acc = cb[d];
    #pragma unroll
    for (int j = 0; j < 4; ++j) {
        int tt = t - 3 + j;
        if (tt >= 0)
            acc += bf2f(u[(size_t)(tok - 3 + j) * D_INNER + d]) * cw[d * 4 + j];
    }
    float s = acc / (1.f + __expf(-acc));
    uc[(size_t)tok * D_INNER + d] = f2bf(s);
}

// ---------------- scan pass 1: per-chunk local end state + sum(dt) ----------------
__global__ __launch_bounds__(256) void scan1(const float* __restrict__ dt,
                                             const u16* __restrict__ uc,
                                             const float* __restrict__ xdbl,
                                             const float* __restrict__ A_log,
                                             float* __restrict__ hend,
                                             float* __restrict__ sdt_out) {
    int d = blockIdx.x * 256 + threadIdx.x;
    int c = blockIdx.y, b = blockIdx.z;
    float a2[NSTATE];
    #pragma unroll
    for (int n = 0; n < NSTATE; ++n)
        a2[n] = -__expf(A_log[d * NSTATE + n]) * LOG2E;
    float h[NSTATE];
    #pragma unroll
    for (int n = 0; n < NSTATE; ++n) h[n] = 0.f;
    float sdt = 0.f;
    int tok0 = b * SEQ + c * CHUNK;
    for (int t = 0; t < CHUNK; ++t) {
        int tok = tok0 + t;
        float dtv = dt[(size_t)tok * D_INNER + d];
        float uv  = bf2f(uc[(size_t)tok * D_INNER + d]);
        float dtu = dtv * uv;
        const float4* Bp = (const float4*)(xdbl + (size_t)tok * 96 + 64);
        float4 B0 = Bp[0], B1 = Bp[1], B2 = Bp[2], B3 = Bp[3];
        float Bv[NSTATE] = {B0.x,B0.y,B0.z,B0.w, B1.x,B1.y,B1.z,B1.w,
                            B2.x,B2.y,B2.z,B2.w, B3.x,B3.y,B3.z,B3.w};
        sdt += dtv;
        #pragma unroll
        for (int n = 0; n < NSTATE; ++n) {
            float da = exp2f(a2[n] * dtv);
            h[n] = fmaf(da, h[n], dtu * Bv[n]);
        }
    }
    sdt_out[(size_t)(b * NCH + c) * D_INNER + d] = sdt;
    #pragma unroll
    for (int n = 0; n < NSTATE; ++n)
        hend[((size_t)(b * NCH + c) * NSTATE + n) * D_INNER + d] = h[n];
}

// ---------------- inter-chunk carry scan (in-place: hend -> carry-in) ----------------
__global__ __launch_bounds__(256) void scan_carry(float* __restrict__ hend,
                                                  const float* __restrict__ sdt,
                                                  const float* __restrict__ A_log) {
    int g = blockIdx.x * 256 + threadIdx.x;     // 65536
    int d = g & (D_INNER - 1);
    int n = (g >> 11) & (NSTATE - 1);
    int b = g >> 15;
    float a2 = -__expf(A_log[d * NSTATE + n]) * LOG2E;
    float H = 0.f;
    for (int c = 0; c < NCH; ++c) {
        size_t off = ((size_t)(b * NCH + c) * NSTATE + n) * D_INNER + d;
        float v = hend[off];
        float p = exp2f(a2 * sdt[(size_t)(b * NCH + c) * D_INNER + d]);
        hend[off] = H;                 // carry-in for chunk c
        H = fmaf(p, H, v);
    }
}

// ---------------- scan pass 2: full recurrence + Dskip + gate -> ys bf16 ----------------
__global__ __launch_bounds__(256) void scan2(const float* __restrict__ dt,
                                             const u16* __restrict__ uc,
                                             const float* __restrict__ xdbl,
                                             const float* __restrict__ A_log,
                                             const float* __restrict__ hin,
                                             const float* __restrict__ Dskip,
                                             const u16* __restrict__ zs,
                                             u16* __restrict__ ys) {
    int d = blockIdx.x * 256 + threadIdx.x;
    int c = blockIdx.y, b = blockIdx.z;
    float a2[NSTATE];
    #pragma unroll
    for (int n = 0; n < NSTATE; ++n)
        a2[n] = -__expf(A_log[d * NSTATE + n]) * LOG2E;
    float h[NSTATE];
    #pragma unroll
    for (int n = 0; n < NSTATE; ++n)
        h[n] = hin[((size_t)(b * NCH + c) * NSTATE + n) * D_INNER + d];
    float Dv = Dskip[d];
    int tok0 = b * SEQ + c * CHUNK;
    for (int t = 0; t < CHUNK; ++t) {
        int tok = tok0 + t;
        float dtv = dt[(size_t)tok * D_INNER + d];
        float uv  = bf2f(uc[(size_t)tok * D_INNER + d]);
        float dtu = dtv * uv;
        const float4* Bp = (const float4*)(xdbl + (size_t)tok * 96 + 64);
        float4 B0 = Bp[0], B1 = Bp[1], B2 = Bp[2], B3 = Bp[3];
        const float4* Cp = (const float4*)(xdbl + (size_t)tok * 96 + 80);
        float4 C0 = Cp[0], C1 = Cp[1], C2 = Cp[2], C3 = Cp[3];
        float Bv[NSTATE] = {B0.x,B0.y,B0.z,B0.w, B1.x,B1.y,B1.z,B1.w,
                            B2.x,B2.y,B2.z,B2.w, B3.x,B3.y,B3.z,B3.w};
        float Cv[NSTATE] = {C0.x,C0.y,C0.z,C0.w, C1.x,C1.y,C1.z,C1.w,
                            C2.x,C2.y,C2.z,C2.w, C3.x,C3.y,C3.z,C3.w};
        float y = 0.f;
        #pragma unroll
        for (int n = 0; n < NSTATE; ++n) {
            float da = exp2f(a2[n] * dtv);
            h[n] = fmaf(da, h[n], dtu * Bv[n]);
            y = fmaf(h[n], Cv[n], y);
        }
        float g = bf2f(zs[(size_t)tok * D_INNER + d]);
        ys[(size_t)tok * D_INNER + d] = f2bf((y + uv * Dv) * g);
    }
}

// ---------------- host launcher ----------------
extern "C" void kernel_launch(void* const* d_in, const int* in_sizes, int n_in,
                              void* d_out, int out_size, void* d_ws, size_t ws_size,
                              hipStream_t stream) {
    const float* x        = (const float*)d_in[0];
    const float* ln_w     = (const float*)d_in[1];
    const float* ln_b     = (const float*)d_in[2];
    const float* in_projw = (const float*)d_in[3];
    const float* conv_w   = (const float*)d_in[4];
    const float* conv_b   = (const float*)d_in[5];
    const float* x_projw  = (const float*)d_in[6];
    const float* dt_projw = (const float*)d_in[7];
    const float* dt_projb = (const float*)d_in[8];
    const float* A_log    = (const float*)d_in[9];
    const float* Dskip    = (const float*)d_in[10];
    const float* out_projw= (const float*)d_in[11];
    float* out = (float*)d_out;

    uint8_t* w = (uint8_t*)d_ws;
    size_t off = 0;
    auto alloc = [&](size_t bytes) { uint8_t* p = w + off; off += (bytes + 255) & ~(size_t)255; return p; };

    u16* w1b   = (u16*)alloc((size_t)4096 * 1024 * 2);
    u16* woutb = (u16*)alloc((size_t)1024 * 2048 * 2);
    u16* xpb   = (u16*)alloc((size_t)96 * 2048 * 2);
    u16* dtwb  = (u16*)alloc((size_t)2048 * 64 * 2);
    u16* y_bf  = (u16*)alloc((size_t)NTOK * 1024 * 2);
    u16* u_bf  = (u16*)alloc((size_t)NTOK * 2048 * 2);   // reused as ys_bf after conv
    u16* zs_bf = (u16*)alloc((size_t)NTOK * 2048 * 2);
    u16* uc_bf = (u16*)alloc((size_t)NTOK * 2048 * 2);
    float* xdbl  = (float*)alloc((size_t)NTOK * 96 * 4);
    u16*   dtinb = (u16*)alloc((size_t)NTOK * 64 * 2);
    float* dt_f  = (float*)alloc((size_t)NTOK * 2048 * 4);
    float* sdt   = (float*)alloc((size_t)BATCH * NCH * 2048 * 4);
    float* hend  = (float*)alloc((size_t)BATCH * NCH * NSTATE * 2048 * 4);
    u16* ys_bf = u_bf;
    (void)ws_size; (void)n_in; (void)in_sizes; (void)out_size;

    // weight casts
    castf2bf<<<1024, 256, 0, stream>>>(in_projw,  w1b,   4096 * 1024);
    castf2bf<<<512,  256, 0, stream>>>(out_projw, woutb, 1024 * 2048);
    castf2bf<<<128,  256, 0, stream>>>(x_projw,   xpb,   96 * 2048);
    castf2bf<<<128,  256, 0, stream>>>(dt_projw,  dtwb,  2048 * 64);

    // LayerNorm -> bf16
    ln_cast<<<NTOK, 256, 0, stream>>>(x, ln_w, ln_b, y_bf);

    // in_proj: [4096,1024] x [4096,1024]^T -> split u / silu(z)
    gemm_bf16<0><<<dim3(32, 32), 256, 0, stream>>>(y_bf, w1b, NTOK, 4096, 1024,
                                                   nullptr, u_bf, zs_bf, nullptr);
    // conv + silu
    conv_silu<<<dim3(8, NTOK), 256, 0, stream>>>(u_bf, conv_w, conv_b, uc_bf);

    // x_proj: [4096,2048] x [96,2048]^T -> xdbl fp32 + dt-input bf16
    gemm_bf16<1><<<dim3(1, 32), 256, 0, stream>>>(uc_bf, xpb, NTOK, 96, 2048,
                                                  xdbl, dtinb, nullptr, nullptr);
    // dt_proj + softplus: [4096,64] x [2048,64]^T
    gemm_bf16<2><<<dim3(16, 32), 256, 0, stream>>>(dtinb, dtwb, NTOK, 2048, 64,
                                                   dt_f, nullptr, nullptr, dt_projb);
    // chunked selective scan
    scan1<<<dim3(8, NCH, BATCH), 256, 0, stream>>>(dt_f, uc_bf, xdbl, A_log, hend, sdt);
    scan_carry<<<256, 256, 0, stream>>>(hend, sdt, A_log);
    scan2<<<dim3(8, NCH, BATCH), 256, 0, stream>>>(dt_f, uc_bf, xdbl, A_log, hend, Dskip, zs_bf, ys_bf);

    // out_proj + residual
    gemm_bf16<3><<<dim3(8, 32), 256, 0, stream>>>(ys_bf, woutb, NTOK, 1024, 2048,
                                                  out, nullptr, nullptr, x);
}

// Round 2
// 414.396 us; speedup vs baseline: 1.2147x; 1.2147x over previous
//
#include <hip/hip_runtime.h>
#include <cstdint>
#include <cstddef>

typedef unsigned short u16;
typedef __attribute__((ext_vector_type(8))) __bf16 bf16x8;
typedef __attribute__((ext_vector_type(8))) u16   u16x8;
typedef __attribute__((ext_vector_type(4))) float f32x4;

#define D_MODEL 1024
#define D_INNER 2048
#define NSTATE  16
#define DT_RANK 64
#define BATCH   2
#define SEQ     2048
#define NTOK    (BATCH*SEQ)      // 4096
#define CHUNK   64
#define NCH     (SEQ/CHUNK)      // 32
#define LOG2E   1.44269504088896340736f

static __device__ __forceinline__ u16 f2bf(float f) {
    uint32_t u = __builtin_bit_cast(uint32_t, f);
    u += 0x7fffu + ((u >> 16) & 1u);          // RNE
    return (u16)(u >> 16);
}
static __device__ __forceinline__ float bf2f(u16 h) {
    uint32_t u = ((uint32_t)h) << 16;
    return __builtin_bit_cast(float, u);
}

// async global->LDS, 16B per lane; lds dest is wave-uniform base + lane*16
static __device__ __forceinline__ void gload16(const u16* g, u16* l) {
    __builtin_amdgcn_global_load_lds(
        (const __attribute__((address_space(1))) void*)g,
        (__attribute__((address_space(3))) void*)l, 16, 0, 0);
}

// ---------------- fused weight casts (+ zero-pad x_proj to 128 rows) ----------------
#define N_W1  (4096*1024)
#define N_WO  (1024*2048)
#define N_XP  (96*2048)
#define N_XPP (128*2048)
#define N_DTW (2048*64)
#define N_ALL (N_W1 + N_WO + N_XPP + N_DTW)

__global__ __launch_bounds__(256) void cast_weights(
    const float* __restrict__ w1, const float* __restrict__ wo,
    const float* __restrict__ xp, const float* __restrict__ dtw,
    u16* __restrict__ o1, u16* __restrict__ oo,
    u16* __restrict__ oxp, u16* __restrict__ odt)
{
    int i = (blockIdx.x * 256 + threadIdx.x) * 4;
    int stride = gridDim.x * 256 * 4;
    for (; i < N_ALL; i += stride) {
        const float* src; u16* dst; int off;
        if (i < N_W1)                { src = w1;  dst = o1;  off = i; }
        else if (i < N_W1 + N_WO)    { src = wo;  dst = oo;  off = i - N_W1; }
        else if (i < N_W1 + N_WO + N_XPP) {
            off = i - N_W1 - N_WO; dst = oxp;
            if (off >= N_XP) { ushort4 z = {0,0,0,0}; *(ushort4*)&oxp[off] = z; continue; }
            src = xp;
        } else                       { src = dtw; dst = odt; off = i - N_W1 - N_WO - N_XPP; }
        float4 v = *(const float4*)&src[off];
        ushort4 o4;
        o4.x = f2bf(v.x); o4.y = f2bf(v.y); o4.z = f2bf(v.z); o4.w = f2bf(v.w);
        *(ushort4*)&dst[off] = o4;
    }
}

// ---------------- LayerNorm + bf16 cast ----------------
__global__ __launch_bounds__(256) void ln_cast(const float* __restrict__ x,
                                               const float* __restrict__ w,
                                               const float* __restrict__ bb,
                                               u16* __restrict__ y) {
    int row = blockIdx.x;
    const float4 v = ((const float4*)(x + (size_t)row * D_MODEL))[threadIdx.x];
    float s  = v.x + v.y + v.z + v.w;
    float sq = v.x*v.x + v.y*v.y + v.z*v.z + v.w*v.w;
    #pragma unroll
    for (int o = 32; o > 0; o >>= 1) {
        s  += __shfl_down(s,  o, 64);
        sq += __shfl_down(sq, o, 64);
    }
    __shared__ float sh[8];
    int wv = threadIdx.x >> 6;
    if ((threadIdx.x & 63) == 0) { sh[wv] = s; sh[4 + wv] = sq; }
    __syncthreads();
    s  = sh[0] + sh[1] + sh[2] + sh[3];
    sq = sh[4] + sh[5] + sh[6] + sh[7];
    float mu  = s * (1.f / D_MODEL);
    float var = sq * (1.f / D_MODEL) - mu * mu;
    float inv = rsqrtf(var + 1e-5f);
    int c = threadIdx.x * 4;
    ushort4 o4;
    o4.x = f2bf((v.x - mu) * inv * w[c+0] + bb[c+0]);
    o4.y = f2bf((v.y - mu) * inv * w[c+1] + bb[c+1]);
    o4.z = f2bf((v.z - mu) * inv * w[c+2] + bb[c+2]);
    o4.w = f2bf((v.w - mu) * inv * w[c+3] + bb[c+3]);
    ((ushort4*)(y + (size_t)row * D_MODEL))[threadIdx.x] = o4;
}

// ---------------- m97-structure bf16 MFMA GEMM: C[M,N] = A[M,K] * B[N,K]^T ----------------
// All dims multiples of 128/64 (x_proj B pre-padded to 128 rows). global_load_lds staging.
// EPI 0: split u/z (N=4096): col<2048 -> u_bf ; col>=2048 -> silu -> zs_bf
// EPI 1: x_proj (N=128 padded): fp32 xdbl[row*96+col] (col<96), bf16 dtin (col<64)
// EPI 2: dt:  softplus(acc + e0[col]) -> fo0[row*N+col]
// EPI 3: out: fo0[row*N+col] = acc + e0[row*N+col]
template<int EPI>
__global__ __launch_bounds__(256) void gemm_bf16(
    const u16* __restrict__ A, const u16* __restrict__ B,
    int N, int K,
    float* __restrict__ fo0, u16* __restrict__ bo0, u16* __restrict__ bo1,
    const float* __restrict__ e0)
{
    __shared__ u16 As[128][64];     // linear, matches global_load_lds lane order
    __shared__ u16 Bs[128][64];
    const int tid  = threadIdx.x;
    const int wid  = tid >> 6, lane = tid & 63;
    const int bm   = blockIdx.y * 128, bn = blockIdx.x * 128;
    const int wm   = (wid >> 1) * 64, wn = (wid & 1) * 64;
    const int lr   = lane & 15, lk = (lane >> 4) * 8;

    // each wave stages 32 A-rows and 32 B-rows per K-step, 4 issues each (8 rows/issue)
    const u16* Ag = A + (size_t)(bm + 32*wid + (lane >> 3)) * K + (lane & 7) * 8;
    const u16* Bg = B + (size_t)(bn + 32*wid + (lane >> 3)) * K + (lane & 7) * 8;
    u16* Al = &As[32*wid][0];
    u16* Bl = &Bs[32*wid][0];

    f32x4 acc[4][4];
    #pragma unroll
    for (int m = 0; m < 4; ++m)
        #pragma unroll
        for (int n = 0; n < 4; ++n)
            #pragma unroll
            for (int r = 0; r < 4; ++r) acc[m][n][r] = 0.f;

    for (int k0 = 0; k0 < K; k0 += 64) {
        #pragma unroll
        for (int i = 0; i < 4; ++i) {
            gload16(Ag + (size_t)(8*i) * K + k0, Al + i * 512);
            gload16(Bg + (size_t)(8*i) * K + k0, Bl + i * 512);
        }
        __syncthreads();            // compiler emits vmcnt(0) drain before barrier
        #pragma unroll
        for (int ks = 0; ks < 2; ++ks) {
            bf16x8 af[4], bfr[4];
            #pragma unroll
            for (int m = 0; m < 4; ++m)
                af[m] = *(const bf16x8*)&As[wm + m*16 + lr][ks*32 + lk];
            #pragma unroll
            for (int n = 0; n < 4; ++n)
                bfr[n] = *(const bf16x8*)&Bs[wn + n*16 + lr][ks*32 + lk];
            #pragma unroll
            for (int m = 0; m < 4; ++m)
                #pragma unroll
                for (int n = 0; n < 4; ++n)
                    acc[m][n] = __builtin_amdgcn_mfma_f32_16x16x32_bf16(af[m], bfr[n], acc[m][n], 0, 0, 0);
        }
        __syncthreads();
    }

    const int cr0 = (lane >> 4) * 4;
    const int cc  = lane & 15;
    #pragma unroll
    for (int m = 0; m < 4; ++m) {
        #pragma unroll
        for (int n = 0; n < 4; ++n) {
            #pragma unroll
            for (int r = 0; r < 4; ++r) {
                int row = bm + wm + m*16 + cr0 + r;
                int col = bn + wn + n*16 + cc;
                float v = acc[m][n][r];
                if (EPI == 0) {
                    if (col < D_INNER) {
                        bo0[(size_t)row * D_INNER + col] = f2bf(v);
                    } else {
                        float s = v / (1.f + __expf(-v));
                        bo1[(size_t)row * D_INNER + (col - D_INNER)] = f2bf(s);
                    }
                } else if (EPI == 1) {
                    if (col < 96) fo0[(size_t)row * 96 + col] = v;
                    if (col < 64) bo0[(size_t)row * 64 + col] = f2bf(v);
                } else if (EPI == 2) {
                    float t = v + e0[col];
                    float sp = (t > 20.f) ? t : log1pf(__expf(t));
                    fo0[(size_t)row * N + col] = sp;
                } else { // EPI == 3
                    fo0[(size_t)row * N + col] = v + e0[(size_t)row * N + col];
                }
            }
        }
    }
}

// ---------------- depthwise causal conv(4) + bias + silu (8 d's / thread) ----------------
__global__ __launch_bounds__(256) void conv_silu(const u16* __restrict__ u,
                                                 const float* __restrict__ cw,
                                                 const float* __restrict__ cb,
                                                 u16* __restrict__ uc) {
    int tok = blockIdx.x;                        // 0..4095
    int d0  = threadIdx.x * 8;                   // 0..2040
    int t   = tok & (SEQ - 1);
    float acc[8];
    {
        float4 b0 = *(const float4*)&cb[d0];
        float4 b1 = *(const float4*)&cb[d0 + 4];
        acc[0]=b0.x; acc[1]=b0.y; acc[2]=b0.z; acc[3]=b0.w;
        acc[4]=b1.x; acc[5]=b1.y; acc[6]=b1.z; acc[7]=b1.w;
    }
    float4 c4[8];
    #pragma unroll
    for (int e = 0; e < 8; ++e) c4[e] = *(const float4*)&cw[(d0 + e) * 4];
    #pragma unroll
    for (int j = 0; j < 4; ++j) {
        int tt = t - 3 + j;
        if (tt < 0) continue;                    // uniform per block
        u16x8 uv = *(const u16x8*)&u[(size_t)(tok - 3 + j) * D_INNER + d0];
        const float* cj = (const float*)c4;
        #pragma unroll
        for (int e = 0; e < 8; ++e)
            acc[e] += bf2f(uv[e]) * cj[e * 4 + j];
    }
    u16x8 o;
    #pragma unroll
    for (int e = 0; e < 8; ++e) {
        float s = acc[e] / (1.f + __expf(-acc[e]));
        o[e] = (__bf16)0;
        ((u16*)&o)[e] = f2bf(s);
    }
    *(u16x8*)&uc[(size_t)tok * D_INNER + d0] = o;
}

// ---------------- scan pass 1: per-chunk local end state + sum(dt) ----------------
__global__ __launch_bounds__(256) void scan1(const float* __restrict__ dt,
                                             const u16* __restrict__ uc,
                                             const float* __restrict__ xdbl,
                                             const float* __restrict__ A_log,
                                             float* __restrict__ hend,
                                             float* __restrict__ sdt_out) {
    int d = blockIdx.x * 256 + threadIdx.x;
    int c = blockIdx.y, b = blockIdx.z;
    float a2[NSTATE];
    #pragma unroll
    for (int n = 0; n < NSTATE; ++n)
        a2[n] = -__expf(A_log[d * NSTATE + n]) * LOG2E;
    float h[NSTATE];
    #pragma unroll
    for (int n = 0; n < NSTATE; ++n) h[n] = 0.f;
    float sdt = 0.f;
    int tok0 = b * SEQ + c * CHUNK;
    for (int t = 0; t < CHUNK; ++t) {
        int tok = tok0 + t;
        float dtv = dt[(size_t)tok * D_INNER + d];
        float uv  = bf2f(uc[(size_t)tok * D_INNER + d]);
        float dtu = dtv * uv;
        const float4* Bp = (const float4*)(xdbl + (size_t)tok * 96 + 64);
        float4 B0 = Bp[0], B1 = Bp[1], B2 = Bp[2], B3 = Bp[3];
        float Bv[NSTATE] = {B0.x,B0.y,B0.z,B0.w, B1.x,B1.y,B1.z,B1.w,
                            B2.x,B2.y,B2.z,B2.w, B3.x,B3.y,B3.z,B3.w};
        sdt += dtv;
        #pragma unroll
        for (int n = 0; n < NSTATE; ++n) {
            float da = exp2f(a2[n] * dtv);
            h[n] = fmaf(da, h[n], dtu * Bv[n]);
        }
    }
    sdt_out[(size_t)(b * NCH + c) * D_INNER + d] = sdt;
    #pragma unroll
    for (int n = 0; n < NSTATE; ++n)
        hend[((size_t)(b * NCH + c) * NSTATE + n) * D_INNER + d] = h[n];
}

// ---------------- inter-chunk carry scan (in-place: hend -> carry-in) ----------------
__global__ __launch_bounds__(256) void scan_carry(float* __restrict__ hend,
                                                  const float* __restrict__ sdt,
                                                  const float* __restrict__ A_log) {
    int g = blockIdx.x * 256 + threadIdx.x;     // 65536
    int d = g & (D_INNER - 1);
    int n = (g >> 11) & (NSTATE - 1);
    int b = g >> 15;
    float a2 = -__expf(A_log[d * NSTATE + n]) * LOG2E;
    float H = 0.f;
    for (int c = 0; c < NCH; ++c) {
        size_t off = ((size_t)(b * NCH + c) * NSTATE + n) * D_INNER + d;
        float v = hend[off];
        float p = exp2f(a2 * sdt[(size_t)(b * NCH + c) * D_INNER + d]);
        hend[off] = H;                 // carry-in for chunk c
        H = fmaf(p, H, v);
    }
}

// ---------------- scan pass 2: full recurrence + Dskip + gate -> ys bf16 ----------------
__global__ __launch_bounds__(256) void scan2(const float* __restrict__ dt,
                                             const u16* __restrict__ uc,
                                             const float* __restrict__ xdbl,
                                             const float* __restrict__ A_log,
                                             const float* __restrict__ hin,
                                             const float* __restrict__ Dskip,
                                             const u16* __restrict__ zs,
                                             u16* __restrict__ ys) {
    int d = blockIdx.x * 256 + threadIdx.x;
    int c = blockIdx.y, b = blockIdx.z;
    float a2[NSTATE];
    #pragma unroll
    for (int n = 0; n < NSTATE; ++n)
        a2[n] = -__expf(A_log[d * NSTATE + n]) * LOG2E;
    float h[NSTATE];
    #pragma unroll
    for (int n = 0; n < NSTATE; ++n)
        h[n] = hin[((size_t)(b * NCH + c) * NSTATE + n) * D_INNER + d];
    float Dv = Dskip[d];
    int tok0 = b * SEQ + c * CHUNK;
    for (int t = 0; t < CHUNK; ++t) {
        int tok = tok0 + t;
        float dtv = dt[(size_t)tok * D_INNER + d];
        float uv  = bf2f(uc[(size_t)tok * D_INNER + d]);
        float dtu = dtv * uv;
        const float4* Bp = (const float4*)(xdbl + (size_t)tok * 96 + 64);
        float4 B0 = Bp[0], B1 = Bp[1], B2 = Bp[2], B3 = Bp[3];
        const float4* Cp = (const float4*)(xdbl + (size_t)tok * 96 + 80);
        float4 C0 = Cp[0], C1 = Cp[1], C2 = Cp[2], C3 = Cp[3];
        float Bv[NSTATE] = {B0.x,B0.y,B0.z,B0.w, B1.x,B1.y,B1.z,B1.w,
                            B2.x,B2.y,B2.z,B2.w, B3.x,B3.y,B3.z,B3.w};
        float Cv[NSTATE] = {C0.x,C0.y,C0.z,C0.w, C1.x,C1.y,C1.z,C1.w,
                            C2.x,C2.y,C2.z,C2.w, C3.x,C3.y,C3.z,C3.w};
        float y = 0.f;
        #pragma unroll
        for (int n = 0; n < NSTATE; ++n) {
            float da = exp2f(a2[n] * dtv);
            h[n] = fmaf(da, h[n], dtu * Bv[n]);
            y = fmaf(h[n], Cv[n], y);
        }
        float g = bf2f(zs[(size_t)tok * D_INNER + d]);
        ys[(size_t)tok * D_INNER + d] = f2bf((y + uv * Dv) * g);
    }
}

// ---------------- host launcher ----------------
extern "C" void kernel_launch(void* const* d_in, const int* in_sizes, int n_in,
                              void* d_out, int out_size, void* d_ws, size_t ws_size,
                              hipStream_t stream) {
    const float* x        = (const float*)d_in[0];
    const float* ln_w     = (const float*)d_in[1];
    const float* ln_b     = (const float*)d_in[2];
    const float* in_projw = (const float*)d_in[3];
    const float* conv_w   = (const float*)d_in[4];
    const float* conv_b   = (const float*)d_in[5];
    const float* x_projw  = (const float*)d_in[6];
    const float* dt_projw = (const float*)d_in[7];
    const float* dt_projb = (const float*)d_in[8];
    const float* A_log    = (const float*)d_in[9];
    const float* Dskip    = (const float*)d_in[10];
    const float* out_projw= (const float*)d_in[11];
    float* out = (float*)d_out;

    uint8_t* w = (uint8_t*)d_ws;
    size_t off = 0;
    auto alloc = [&](size_t bytes) { uint8_t* p = w + off; off += (bytes + 255) & ~(size_t)255; return p; };

    u16* w1b   = (u16*)alloc((size_t)N_W1 * 2);
    u16* woutb = (u16*)alloc((size_t)N_WO * 2);
    u16* xpb   = (u16*)alloc((size_t)N_XPP * 2);   // padded to 128 rows
    u16* dtwb  = (u16*)alloc((size_t)N_DTW * 2);
    u16* y_bf  = (u16*)alloc((size_t)NTOK * 1024 * 2);
    u16* u_bf  = (u16*)alloc((size_t)NTOK * 2048 * 2);   // reused as ys_bf after conv
    u16* zs_bf = (u16*)alloc((size_t)NTOK * 2048 * 2);
    u16* uc_bf = (u16*)alloc((size_t)NTOK * 2048 * 2);
    float* xdbl  = (float*)alloc((size_t)NTOK * 96 * 4);
    u16*   dtinb = (u16*)alloc((size_t)NTOK * 64 * 2);
    float* dt_f  = (float*)alloc((size_t)NTOK * 2048 * 4);
    float* sdt   = (float*)alloc((size_t)BATCH * NCH * 2048 * 4);
    float* hend  = (float*)alloc((size_t)BATCH * NCH * NSTATE * 2048 * 4);
    u16* ys_bf = u_bf;
    (void)ws_size; (void)n_in; (void)in_sizes; (void)out_size;

    // fused weight casts (+ x_proj zero-pad)
    cast_weights<<<2048, 256, 0, stream>>>(in_projw, out_projw, x_projw, dt_projw,
                                           w1b, woutb, xpb, dtwb);

    // LayerNorm -> bf16
    ln_cast<<<NTOK, 256, 0, stream>>>(x, ln_w, ln_b, y_bf);

    // in_proj: [4096,1024] x [4096,1024]^T -> split u / silu(z)
    gemm_bf16<0><<<dim3(32, 32), 256, 0, stream>>>(y_bf, w1b, 4096, 1024,
                                                   nullptr, u_bf, zs_bf, nullptr);
    // conv + silu
    conv_silu<<<NTOK, 256, 0, stream>>>(u_bf, conv_w, conv_b, uc_bf);

    // x_proj: [4096,2048] x [128(pad),2048]^T -> xdbl fp32 + dt-input bf16
    gemm_bf16<1><<<dim3(1, 32), 256, 0, stream>>>(uc_bf, xpb, 128, 2048,
                                                  xdbl, dtinb, nullptr, nullptr);
    // dt_proj + softplus: [4096,64] x [2048,64]^T
    gemm_bf16<2><<<dim3(16, 32), 256, 0, stream>>>(dtinb, dtwb, 2048, 64,
                                                   dt_f, nullptr, nullptr, dt_projb);
    // chunked selective scan
    scan1<<<dim3(8, NCH, BATCH), 256, 0, stream>>>(dt_f, uc_bf, xdbl, A_log, hend, sdt);
    scan_carry<<<256, 256, 0, stream>>>(hend, sdt, A_log);
    scan2<<<dim3(8, NCH, BATCH), 256, 0, stream>>>(dt_f, uc_bf, xdbl, A_log, hend, Dskip, zs_bf, ys_bf);

    // out_proj + residual
    gemm_bf16<3><<<dim3(8, 32), 256, 0, stream>>>(ys_bf, woutb, 1024, 2048,
                                                  out, nullptr, nullptr, x);
}

// Round 3
// 330.023 us; speedup vs baseline: 1.5253x; 1.2557x over previous
//
#include <hip/hip_runtime.h>
#include <cstdint>
#include <cstddef>

typedef unsigned short u16;
typedef __attribute__((ext_vector_type(8))) __bf16 bf16x8;
typedef __attribute__((ext_vector_type(8))) u16   u16x8;
typedef __attribute__((ext_vector_type(4))) float f32x4;

#define D_MODEL 1024
#define D_INNER 2048
#define NSTATE  16
#define DT_RANK 64
#define BATCH   2
#define SEQ     2048
#define NTOK    (BATCH*SEQ)      // 4096
#define CHUNK   64
#define NCH     (SEQ/CHUNK)      // 32
#define LOG2E   1.44269504088896340736f

static __device__ __forceinline__ u16 f2bf(float f) {
    uint32_t u = __builtin_bit_cast(uint32_t, f);
    u += 0x7fffu + ((u >> 16) & 1u);          // RNE
    return (u16)(u >> 16);
}
static __device__ __forceinline__ float bf2f(u16 h) {
    uint32_t u = ((uint32_t)h) << 16;
    return __builtin_bit_cast(float, u);
}

// async global->LDS, 16B per lane; lds dest is wave-uniform base + lane*16
static __device__ __forceinline__ void gload16(const u16* g, u16* l) {
    __builtin_amdgcn_global_load_lds(
        (const __attribute__((address_space(1))) void*)g,
        (__attribute__((address_space(3))) void*)l, 16, 0, 0);
}

// bijective XCD-aware swizzle (nwg % 8 == 0), N-tile fastest within an XCD chunk
static __device__ __forceinline__ void xcd_swz(int bid, int nwg, int ntn, int& bm, int& bn) {
    int q  = nwg >> 3;
    int nb = (bid & 7) * q + (bid >> 3);
    bm = nb / ntn;
    bn = nb - bm * ntn;
}

// ---------------- fused weight casts (+ zero-pad x_proj to 128 rows) ----------------
#define N_W1  (4096*1024)
#define N_WO  (1024*2048)
#define N_XP  (96*2048)
#define N_XPP (128*2048)
#define N_DTW (2048*64)
#define N_ALL (N_W1 + N_WO + N_XPP + N_DTW)

__global__ __launch_bounds__(256) void cast_weights(
    const float* __restrict__ w1, const float* __restrict__ wo,
    const float* __restrict__ xp, const float* __restrict__ dtw,
    u16* __restrict__ o1, u16* __restrict__ oo,
    u16* __restrict__ oxp, u16* __restrict__ odt)
{
    int i = (blockIdx.x * 256 + threadIdx.x) * 4;
    int stride = gridDim.x * 256 * 4;
    for (; i < N_ALL; i += stride) {
        const float* src; u16* dst; int off;
        if (i < N_W1)                { src = w1;  dst = o1;  off = i; }
        else if (i < N_W1 + N_WO)    { src = wo;  dst = oo;  off = i - N_W1; }
        else if (i < N_W1 + N_WO + N_XPP) {
            off = i - N_W1 - N_WO; dst = oxp;
            if (off >= N_XP) { ushort4 z = {0,0,0,0}; *(ushort4*)&oxp[off] = z; continue; }
            src = xp;
        } else                       { src = dtw; dst = odt; off = i - N_W1 - N_WO - N_XPP; }
        float4 v = *(const float4*)&src[off];
        ushort4 o4;
        o4.x = f2bf(v.x); o4.y = f2bf(v.y); o4.z = f2bf(v.z); o4.w = f2bf(v.w);
        *(ushort4*)&dst[off] = o4;
    }
}

// ---------------- LayerNorm + bf16 cast ----------------
__global__ __launch_bounds__(256) void ln_cast(const float* __restrict__ x,
                                               const float* __restrict__ w,
                                               const float* __restrict__ bb,
                                               u16* __restrict__ y) {
    int row = blockIdx.x;
    const float4 v = ((const float4*)(x + (size_t)row * D_MODEL))[threadIdx.x];
    float s  = v.x + v.y + v.z + v.w;
    float sq = v.x*v.x + v.y*v.y + v.z*v.z + v.w*v.w;
    #pragma unroll
    for (int o = 32; o > 0; o >>= 1) {
        s  += __shfl_down(s,  o, 64);
        sq += __shfl_down(sq, o, 64);
    }
    __shared__ float sh[8];
    int wv = threadIdx.x >> 6;
    if ((threadIdx.x & 63) == 0) { sh[wv] = s; sh[4 + wv] = sq; }
    __syncthreads();
    s  = sh[0] + sh[1] + sh[2] + sh[3];
    sq = sh[4] + sh[5] + sh[6] + sh[7];
    float mu  = s * (1.f / D_MODEL);
    float var = sq * (1.f / D_MODEL) - mu * mu;
    float inv = rsqrtf(var + 1e-5f);
    int c = threadIdx.x * 4;
    ushort4 o4;
    o4.x = f2bf((v.x - mu) * inv * w[c+0] + bb[c+0]);
    o4.y = f2bf((v.y - mu) * inv * w[c+1] + bb[c+1]);
    o4.z = f2bf((v.z - mu) * inv * w[c+2] + bb[c+2]);
    o4.w = f2bf((v.w - mu) * inv * w[c+3] + bb[c+3]);
    ((ushort4*)(y + (size_t)row * D_MODEL))[threadIdx.x] = o4;
}

// ---------------- prefetch-dbuf bf16 MFMA GEMM core: C = A[M,K] * B[N,K]^T ----------------
// EPI 0: split u/z (N=4096): col<2048 -> u_bf ; col>=2048 -> silu -> zs_bf
// EPI 1: x_proj (N=128 padded): fp32 xdbl[row*96+col] (col<96), bf16 dtin (col<64)
// EPI 2: dt:  softplus(acc + e0[col]) -> bf16 bo0[row*2048+col]
// EPI 3: out: fo0[row*1024+col] = acc + e0[row*1024+col]
template<int EPI>
static __device__ __forceinline__ void gemm_core(
    const u16* __restrict__ A, const u16* __restrict__ B,
    int bm, int bn, int K,
    float* __restrict__ fo0, u16* __restrict__ bo0, u16* __restrict__ bo1,
    const float* __restrict__ e0)
{
    __shared__ u16 As[2][128 * 64];   // 32 KB
    __shared__ u16 Bs[2][128 * 64];   // 32 KB
    const int tid  = threadIdx.x;
    const int wid  = tid >> 6, lane = tid & 63;
    const int wm   = (wid >> 1) * 64, wn = (wid & 1) * 64;
    const int lr   = lane & 15, lk = (lane >> 4) * 8;

    // each wave stages 32 A-rows and 32 B-rows per K-step, 4 issues each (8 rows/issue)
    const u16* Ag = A + (size_t)(bm + 32*wid + (lane >> 3)) * K + (lane & 7) * 8;
    const u16* Bg = B + (size_t)(bn + 32*wid + (lane >> 3)) * K + (lane & 7) * 8;
    const int lbase = wid * 2048;

    f32x4 acc[4][4];
    #pragma unroll
    for (int m = 0; m < 4; ++m)
        #pragma unroll
        for (int n = 0; n < 4; ++n)
            #pragma unroll
            for (int r = 0; r < 4; ++r) acc[m][n][r] = 0.f;

    auto stage = [&](int buf, int k0) {
        #pragma unroll
        for (int i = 0; i < 4; ++i) {
            gload16(Ag + (size_t)(8*i) * K + k0, &As[buf][lbase + i * 512]);
            gload16(Bg + (size_t)(8*i) * K + k0, &Bs[buf][lbase + i * 512]);
        }
    };

    const int nt = K >> 6;
    stage(0, 0);
    for (int t = 0; t < nt; ++t) {
        __syncthreads();                 // drains vmcnt: tile t resident; syncs buf reuse
        if (t + 1 < nt) stage((t + 1) & 1, (t + 1) << 6);
        const int cb = t & 1;
        #pragma unroll
        for (int ks = 0; ks < 2; ++ks) {
            bf16x8 af[4], bfr[4];
            #pragma unroll
            for (int m = 0; m < 4; ++m)
                af[m] = *(const bf16x8*)&As[cb][(wm + m*16 + lr) * 64 + ks*32 + lk];
            #pragma unroll
            for (int n = 0; n < 4; ++n)
                bfr[n] = *(const bf16x8*)&Bs[cb][(wn + n*16 + lr) * 64 + ks*32 + lk];
            #pragma unroll
            for (int m = 0; m < 4; ++m)
                #pragma unroll
                for (int n = 0; n < 4; ++n)
                    acc[m][n] = __builtin_amdgcn_mfma_f32_16x16x32_bf16(af[m], bfr[n], acc[m][n], 0, 0, 0);
        }
    }

    const int cr0 = (lane >> 4) * 4;
    const int cc  = lane & 15;
    #pragma unroll
    for (int m = 0; m < 4; ++m) {
        #pragma unroll
        for (int n = 0; n < 4; ++n) {
            #pragma unroll
            for (int r = 0; r < 4; ++r) {
                int row = bm + wm + m*16 + cr0 + r;
                int col = bn + wn + n*16 + cc;
                float v = acc[m][n][r];
                if (EPI == 0) {
                    if (col < D_INNER) {
                        bo0[(size_t)row * D_INNER + col] = f2bf(v);
                    } else {
                        float s = v / (1.f + __expf(-v));
                        bo1[(size_t)row * D_INNER + (col - D_INNER)] = f2bf(s);
                    }
                } else if (EPI == 1) {
                    if (col < 96) fo0[(size_t)row * 96 + col] = v;
                    if (col < 64) bo0[(size_t)row * 64 + col] = f2bf(v);
                } else if (EPI == 2) {
                    float t2 = v + e0[col];
                    float sp = fmaxf(t2, 0.f) + __logf(1.f + __expf(-fabsf(t2)));
                    bo0[(size_t)row * D_INNER + col] = f2bf(sp);
                } else { // EPI == 3
                    fo0[(size_t)row * 1024 + col] = v + e0[(size_t)row * 1024 + col];
                }
            }
        }
    }
}

__global__ __launch_bounds__(256) void gemm_in(const u16* __restrict__ A, const u16* __restrict__ B,
                                               u16* __restrict__ u_out, u16* __restrict__ z_out) {
    int bm, bn; xcd_swz(blockIdx.x, 32 * 32, 32, bm, bn);
    gemm_core<0>(A, B, bm * 128, bn * 128, 1024, nullptr, u_out, z_out, nullptr);
}
__global__ __launch_bounds__(256) void gemm_xp(const u16* __restrict__ A, const u16* __restrict__ B,
                                               float* __restrict__ xdbl, u16* __restrict__ dtin) {
    int bm, bn; xcd_swz(blockIdx.x, 32, 1, bm, bn);
    gemm_core<1>(A, B, bm * 128, bn * 128, 2048, xdbl, dtin, nullptr, nullptr);
}
__global__ __launch_bounds__(256) void gemm_dt(const u16* __restrict__ A, const u16* __restrict__ B,
                                               u16* __restrict__ dtb, const float* __restrict__ bias) {
    int bm, bn; xcd_swz(blockIdx.x, 16 * 32, 16, bm, bn);
    gemm_core<2>(A, B, bm * 128, bn * 128, 64, nullptr, dtb, nullptr, bias);
}
__global__ __launch_bounds__(256) void gemm_out(const u16* __restrict__ A, const u16* __restrict__ B,
                                                float* __restrict__ out, const float* __restrict__ resid) {
    int bm, bn; xcd_swz(blockIdx.x, 8 * 32, 8, bm, bn);
    gemm_core<3>(A, B, bm * 128, bn * 128, 2048, out, nullptr, nullptr, resid);
}

// ---------------- depthwise causal conv(4) + bias + silu (8 d's / thread) ----------------
__global__ __launch_bounds__(256) void conv_silu(const u16* __restrict__ u,
                                                 const float* __restrict__ cw,
                                                 const float* __restrict__ cb,
                                                 u16* __restrict__ uc) {
    int tok = blockIdx.x;                        // 0..4095
    int d0  = threadIdx.x * 8;                   // 0..2040
    int t   = tok & (SEQ - 1);
    float acc[8];
    {
        float4 b0 = *(const float4*)&cb[d0];
        float4 b1 = *(const float4*)&cb[d0 + 4];
        acc[0]=b0.x; acc[1]=b0.y; acc[2]=b0.z; acc[3]=b0.w;
        acc[4]=b1.x; acc[5]=b1.y; acc[6]=b1.z; acc[7]=b1.w;
    }
    float4 c4[8];
    #pragma unroll
    for (int e = 0; e < 8; ++e) c4[e] = *(const float4*)&cw[(d0 + e) * 4];
    #pragma unroll
    for (int j = 0; j < 4; ++j) {
        int tt = t - 3 + j;
        if (tt < 0) continue;                    // uniform per block
        u16x8 uv = *(const u16x8*)&u[(size_t)(tok - 3 + j) * D_INNER + d0];
        const float* cj = (const float*)c4;
        #pragma unroll
        for (int e = 0; e < 8; ++e)
            acc[e] += bf2f(uv[e]) * cj[e * 4 + j];
    }
    u16x8 o;
    #pragma unroll
    for (int e = 0; e < 8; ++e) {
        float s = acc[e] / (1.f + __expf(-acc[e]));
        ((u16*)&o)[e] = f2bf(s);
    }
    *(u16x8*)&uc[(size_t)tok * D_INNER + d0] = o;
}

// ---------------- scan pass 1: per-chunk local end state + sum(dt) ----------------
__global__ __launch_bounds__(256) void scan1(const u16* __restrict__ dtb,
                                             const u16* __restrict__ uc,
                                             const float* __restrict__ xdbl,
                                             const float* __restrict__ A_log,
                                             float* __restrict__ hend,
                                             float* __restrict__ sdt_out) {
    int d = blockIdx.x * 256 + threadIdx.x;
    int c = blockIdx.y, b = blockIdx.z;
    float a2[NSTATE];
    #pragma unroll
    for (int n = 0; n < NSTATE; ++n)
        a2[n] = -__expf(A_log[d * NSTATE + n]) * LOG2E;
    float h[NSTATE];
    #pragma unroll
    for (int n = 0; n < NSTATE; ++n) h[n] = 0.f;
    float sdt = 0.f;
    int tok0 = b * SEQ + c * CHUNK;
    for (int t = 0; t < CHUNK; ++t) {
        int tok = tok0 + t;
        float dtv = bf2f(dtb[(size_t)tok * D_INNER + d]);
        float uv  = bf2f(uc[(size_t)tok * D_INNER + d]);
        float dtu = dtv * uv;
        const float4* Bp = (const float4*)(xdbl + (size_t)tok * 96 + 64);
        float4 B0 = Bp[0], B1 = Bp[1], B2 = Bp[2], B3 = Bp[3];
        float Bv[NSTATE] = {B0.x,B0.y,B0.z,B0.w, B1.x,B1.y,B1.z,B1.w,
                            B2.x,B2.y,B2.z,B2.w, B3.x,B3.y,B3.z,B3.w};
        sdt += dtv;
        #pragma unroll
        for (int n = 0; n < NSTATE; ++n) {
            float da = exp2f(a2[n] * dtv);
            h[n] = fmaf(da, h[n], dtu * Bv[n]);
        }
    }
    sdt_out[(size_t)(b * NCH + c) * D_INNER + d] = sdt;
    #pragma unroll
    for (int n = 0; n < NSTATE; ++n)
        hend[((size_t)(b * NCH + c) * NSTATE + n) * D_INNER + d] = h[n];
}

// ---------------- inter-chunk carry scan (in-place: hend -> carry-in) ----------------
__global__ __launch_bounds__(256) void scan_carry(float* __restrict__ hend,
                                                  const float* __restrict__ sdt,
                                                  const float* __restrict__ A_log) {
    int g = blockIdx.x * 256 + threadIdx.x;     // 65536
    int d = g & (D_INNER - 1);
    int n = (g >> 11) & (NSTATE - 1);
    int b = g >> 15;
    float a2 = -__expf(A_log[d * NSTATE + n]) * LOG2E;
    float H = 0.f;
    for (int c = 0; c < NCH; ++c) {
        size_t off = ((size_t)(b * NCH + c) * NSTATE + n) * D_INNER + d;
        float v = hend[off];
        float p = exp2f(a2 * sdt[(size_t)(b * NCH + c) * D_INNER + d]);
        hend[off] = H;                 // carry-in for chunk c
        H = fmaf(p, H, v);
    }
}

// ---------------- scan pass 2: full recurrence + Dskip + gate -> ys bf16 ----------------
__global__ __launch_bounds__(256) void scan2(const u16* __restrict__ dtb,
                                             const u16* __restrict__ uc,
                                             const float* __restrict__ xdbl,
                                             const float* __restrict__ A_log,
                                             const float* __restrict__ hin,
                                             const float* __restrict__ Dskip,
                                             const u16* __restrict__ zs,
                                             u16* __restrict__ ys) {
    int d = blockIdx.x * 256 + threadIdx.x;
    int c = blockIdx.y, b = blockIdx.z;
    float a2[NSTATE];
    #pragma unroll
    for (int n = 0; n < NSTATE; ++n)
        a2[n] = -__expf(A_log[d * NSTATE + n]) * LOG2E;
    float h[NSTATE];
    #pragma unroll
    for (int n = 0; n < NSTATE; ++n)
        h[n] = hin[((size_t)(b * NCH + c) * NSTATE + n) * D_INNER + d];
    float Dv = Dskip[d];
    int tok0 = b * SEQ + c * CHUNK;
    for (int t = 0; t < CHUNK; ++t) {
        int tok = tok0 + t;
        float dtv = bf2f(dtb[(size_t)tok * D_INNER + d]);
        float uv  = bf2f(uc[(size_t)tok * D_INNER + d]);
        float dtu = dtv * uv;
        const float4* Bp = (const float4*)(xdbl + (size_t)tok * 96 + 64);
        float4 B0 = Bp[0], B1 = Bp[1], B2 = Bp[2], B3 = Bp[3];
        const float4* Cp = (const float4*)(xdbl + (size_t)tok * 96 + 80);
        float4 C0 = Cp[0], C1 = Cp[1], C2 = Cp[2], C3 = Cp[3];
        float Bv[NSTATE] = {B0.x,B0.y,B0.z,B0.w, B1.x,B1.y,B1.z,B1.w,
                            B2.x,B2.y,B2.z,B2.w, B3.x,B3.y,B3.z,B3.w};
        float Cv[NSTATE] = {C0.x,C0.y,C0.z,C0.w, C1.x,C1.y,C1.z,C1.w,
                            C2.x,C2.y,C2.z,C2.w, C3.x,C3.y,C3.z,C3.w};
        float y = 0.f;
        #pragma unroll
        for (int n = 0; n < NSTATE; ++n) {
            float da = exp2f(a2[n] * dtv);
            h[n] = fmaf(da, h[n], dtu * Bv[n]);
            y = fmaf(h[n], Cv[n], y);
        }
        float g = bf2f(zs[(size_t)tok * D_INNER + d]);
        ys[(size_t)tok * D_INNER + d] = f2bf((y + uv * Dv) * g);
    }
}

// ---------------- host launcher ----------------
extern "C" void kernel_launch(void* const* d_in, const int* in_sizes, int n_in,
                              void* d_out, int out_size, void* d_ws, size_t ws_size,
                              hipStream_t stream) {
    const float* x        = (const float*)d_in[0];
    const float* ln_w     = (const float*)d_in[1];
    const float* ln_b     = (const float*)d_in[2];
    const float* in_projw = (const float*)d_in[3];
    const float* conv_w   = (const float*)d_in[4];
    const float* conv_b   = (const float*)d_in[5];
    const float* x_projw  = (const float*)d_in[6];
    const float* dt_projw = (const float*)d_in[7];
    const float* dt_projb = (const float*)d_in[8];
    const float* A_log    = (const float*)d_in[9];
    const float* Dskip    = (const float*)d_in[10];
    const float* out_projw= (const float*)d_in[11];
    float* out = (float*)d_out;

    uint8_t* w = (uint8_t*)d_ws;
    size_t off = 0;
    auto alloc = [&](size_t bytes) { uint8_t* p = w + off; off += (bytes + 255) & ~(size_t)255; return p; };

    u16* w1b   = (u16*)alloc((size_t)N_W1 * 2);
    u16* woutb = (u16*)alloc((size_t)N_WO * 2);
    u16* xpb   = (u16*)alloc((size_t)N_XPP * 2);   // padded to 128 rows
    u16* dtwb  = (u16*)alloc((size_t)N_DTW * 2);
    u16* y_bf  = (u16*)alloc((size_t)NTOK * 1024 * 2);
    u16* u_bf  = (u16*)alloc((size_t)NTOK * 2048 * 2);   // reused as ys_bf after conv
    u16* zs_bf = (u16*)alloc((size_t)NTOK * 2048 * 2);
    u16* uc_bf = (u16*)alloc((size_t)NTOK * 2048 * 2);
    float* xdbl  = (float*)alloc((size_t)NTOK * 96 * 4);
    u16*   dtinb = (u16*)alloc((size_t)NTOK * 64 * 2);
    u16*   dt_bf = (u16*)alloc((size_t)NTOK * 2048 * 2);
    float* sdt   = (float*)alloc((size_t)BATCH * NCH * 2048 * 4);
    float* hend  = (float*)alloc((size_t)BATCH * NCH * NSTATE * 2048 * 4);
    u16* ys_bf = u_bf;
    (void)ws_size; (void)n_in; (void)in_sizes; (void)out_size;

    // fused weight casts (+ x_proj zero-pad)
    cast_weights<<<2048, 256, 0, stream>>>(in_projw, out_projw, x_projw, dt_projw,
                                           w1b, woutb, xpb, dtwb);

    // LayerNorm -> bf16
    ln_cast<<<NTOK, 256, 0, stream>>>(x, ln_w, ln_b, y_bf);

    // in_proj: [4096,1024] x [4096,1024]^T -> split u / silu(z)
    gemm_in<<<1024, 256, 0, stream>>>(y_bf, w1b, u_bf, zs_bf);
    // conv + silu
    conv_silu<<<NTOK, 256, 0, stream>>>(u_bf, conv_w, conv_b, uc_bf);

    // x_proj: [4096,2048] x [128(pad),2048]^T -> xdbl fp32 + dt-input bf16
    gemm_xp<<<32, 256, 0, stream>>>(uc_bf, xpb, xdbl, dtinb);
    // dt_proj + softplus -> bf16: [4096,64] x [2048,64]^T
    gemm_dt<<<512, 256, 0, stream>>>(dtinb, dtwb, dt_bf, dt_projb);

    // chunked selective scan
    scan1<<<dim3(8, NCH, BATCH), 256, 0, stream>>>(dt_bf, uc_bf, xdbl, A_log, hend, sdt);
    scan_carry<<<256, 256, 0, stream>>>(hend, sdt, A_log);
    scan2<<<dim3(8, NCH, BATCH), 256, 0, stream>>>(dt_bf, uc_bf, xdbl, A_log, hend, Dskip, zs_bf, ys_bf);

    // out_proj + residual
    gemm_out<<<256, 256, 0, stream>>>(ys_bf, woutb, out, x);
}

// Round 4
// 316.813 us; speedup vs baseline: 1.5889x; 1.0417x over previous
//
#include <hip/hip_runtime.h>
#include <cstdint>
#include <cstddef>

typedef unsigned short u16;
typedef __attribute__((ext_vector_type(8))) __bf16 bf16x8;
typedef __attribute__((ext_vector_type(8))) u16   u16x8;
typedef __attribute__((ext_vector_type(4))) float f32x4;

#define D_MODEL 1024
#define D_INNER 2048
#define NSTATE  16
#define DT_RANK 64
#define BATCH   2
#define SEQ     2048
#define NTOK    (BATCH*SEQ)      // 4096
#define CHUNK   64
#define NCH     (SEQ/CHUNK)      // 32
#define LOG2E   1.44269504088896340736f

#define VMCNT(n) asm volatile("s_waitcnt vmcnt(" #n ")" ::: "memory")

static __device__ __forceinline__ u16 f2bf(float f) {
    uint32_t u = __builtin_bit_cast(uint32_t, f);
    u += 0x7fffu + ((u >> 16) & 1u);          // RNE
    return (u16)(u >> 16);
}
static __device__ __forceinline__ float bf2f(u16 h) {
    uint32_t u = ((uint32_t)h) << 16;
    return __builtin_bit_cast(float, u);
}

// async global->LDS, 16B per lane; lds dest is wave-uniform base + lane*16
static __device__ __forceinline__ void gload16(const u16* g, u16* l) {
    __builtin_amdgcn_global_load_lds(
        (const __attribute__((address_space(1))) void*)g,
        (__attribute__((address_space(3))) void*)l, 16, 0, 0);
}

// ---------------- fused weight casts (+ zero-pad x_proj to 128 rows) ----------------
#define N_W1  (4096*1024)
#define N_WO  (1024*2048)
#define N_XP  (96*2048)
#define N_XPP (128*2048)
#define N_DTW (2048*64)
#define N_ALL (N_W1 + N_WO + N_XPP + N_DTW)

__global__ __launch_bounds__(256) void cast_weights(
    const float* __restrict__ w1, const float* __restrict__ wo,
    const float* __restrict__ xp, const float* __restrict__ dtw,
    u16* __restrict__ o1, u16* __restrict__ oo,
    u16* __restrict__ oxp, u16* __restrict__ odt)
{
    int i = (blockIdx.x * 256 + threadIdx.x) * 4;
    int stride = gridDim.x * 256 * 4;
    for (; i < N_ALL; i += stride) {
        const float* src; u16* dst; int off;
        if (i < N_W1)                { src = w1;  dst = o1;  off = i; }
        else if (i < N_W1 + N_WO)    { src = wo;  dst = oo;  off = i - N_W1; }
        else if (i < N_W1 + N_WO + N_XPP) {
            off = i - N_W1 - N_WO; dst = oxp;
            if (off >= N_XP) { ushort4 z = {0,0,0,0}; *(ushort4*)&oxp[off] = z; continue; }
            src = xp;
        } else                       { src = dtw; dst = odt; off = i - N_W1 - N_WO - N_XPP; }
        float4 v = *(const float4*)&src[off];
        ushort4 o4;
        o4.x = f2bf(v.x); o4.y = f2bf(v.y); o4.z = f2bf(v.z); o4.w = f2bf(v.w);
        *(ushort4*)&dst[off] = o4;
    }
}

// ---------------- LayerNorm + bf16 cast ----------------
__global__ __launch_bounds__(256) void ln_cast(const float* __restrict__ x,
                                               const float* __restrict__ w,
                                               const float* __restrict__ bb,
                                               u16* __restrict__ y) {
    int row = blockIdx.x;
    const float4 v = ((const float4*)(x + (size_t)row * D_MODEL))[threadIdx.x];
    float s  = v.x + v.y + v.z + v.w;
    float sq = v.x*v.x + v.y*v.y + v.z*v.z + v.w*v.w;
    #pragma unroll
    for (int o = 32; o > 0; o >>= 1) {
        s  += __shfl_down(s,  o, 64);
        sq += __shfl_down(sq, o, 64);
    }
    __shared__ float sh[8];
    int wv = threadIdx.x >> 6;
    if ((threadIdx.x & 63) == 0) { sh[wv] = s; sh[4 + wv] = sq; }
    __syncthreads();
    s  = sh[0] + sh[1] + sh[2] + sh[3];
    sq = sh[4] + sh[5] + sh[6] + sh[7];
    float mu  = s * (1.f / D_MODEL);
    float var = sq * (1.f / D_MODEL) - mu * mu;
    float inv = rsqrtf(var + 1e-5f);
    int c = threadIdx.x * 4;
    ushort4 o4;
    o4.x = f2bf((v.x - mu) * inv * w[c+0] + bb[c+0]);
    o4.y = f2bf((v.y - mu) * inv * w[c+1] + bb[c+1]);
    o4.z = f2bf((v.z - mu) * inv * w[c+2] + bb[c+2]);
    o4.w = f2bf((v.w - mu) * inv * w[c+3] + bb[c+3]);
    ((ushort4*)(y + (size_t)row * D_MODEL))[threadIdx.x] = o4;
}

// ================= 256x256 8-wave phase-pipelined bf16 GEMM =================
// C[M,N] = A[M,K] * B[N,K]^T.  512 thr = 8 waves (2 wr x 4 wc), per-wave 128x64.
// LDS 128 KB: [dbuf2][mat2][half2][128x64 bf16], strict double-buffer: group kt
// reads dbuf[kt&1], stages kt+1 into the OTHER dbuf (no read/write overlap).
// XOR bank-swizzle (key=(row&7)<<4) applied on the global SOURCE address for
// global_load_lds (linear LDS write) and on the ds_read address (rule #21).
// Per K-tile: 4 phases x {ds_read frags, stage 2 half-issues, counted vmcnt,
// barrier, setprio(1), 16 MFMA, setprio(0), barrier}.  vmcnt(4)@p1, vmcnt(2)@p3.
// EPI 0: split u/z (N=4096).  EPI 3: out = acc + resid (N=1024).
template<int EPI, int K, int NTN, int NWG>
__global__ __launch_bounds__(512, 2) void gemm256(
    const u16* __restrict__ A, const u16* __restrict__ B,
    float* __restrict__ fo0, u16* __restrict__ bo0, u16* __restrict__ bo1,
    const float* __restrict__ e0)
{
    __shared__ u16 lds[65536];   // 128 KB
    const int tid = threadIdx.x, wid = tid >> 6, lane = tid & 63;
    const int wr = wid >> 2, wc = wid & 3, lr = lane & 15;
    // bijective XCD swizzle (NWG % 8 == 0)
    const int nb = (blockIdx.x & 7) * (NWG >> 3) + (blockIdx.x >> 3);
    const int bm = (nb / NTN) * 256, bn = (nb % NTN) * 256;

    // staging: per phase each thread issues gload16s; lane covers row
    // srow = wid*8 + lane>>3 (+ half*128 + j*64), source col pre-swizzled
    const int srow = wid * 8 + (lane >> 3);
    const int scol = 8 * ((lane & 7) ^ ((lane >> 3) & 7));
    const u16* Asrc = A + (size_t)(bm + srow) * K + scol;
    const u16* Bsrc = B + (size_t)(bn + srow) * K + scol;
    const int dwave = wid * 512;

    auto stg = [&](int buf, int kt, int mat, int half, int j) {
        gload16((mat ? Bsrc : Asrc) + (size_t)(half * 128 + j * 64) * K + kt * 64,
                &lds[buf * 32768 + mat * 16384 + half * 8192 + j * 4096 + dwave]);
    };

    // ds_read addressing (elem units), swizzled: off = row*64 + acol[kk]
    const int key   = (lr & 7) << 4;
    const int acol0 = (((lane >> 4) * 16) ^ key) >> 1;
    const int acol1 = ((64 | ((lane >> 4) * 16)) ^ key) >> 1;
    const int arow  = lr * 64;
    const int abase = wr * 8192;                               // + cur
    const int bbase = 16384 + (wc >> 1) * 8192 + (wc & 1) * 4096; // + cur

    f32x4 acc[8][4];
    #pragma unroll
    for (int m = 0; m < 8; ++m)
        #pragma unroll
        for (int n = 0; n < 4; ++n)
            #pragma unroll
            for (int r = 0; r < 4; ++r) acc[m][n][r] = 0.f;

    // prologue: stage group 0 into dbuf0 (order B.h0, B.h1, A.i0s, A.i1s)
    stg(0, 0, 1, 0, 0); stg(0, 0, 1, 0, 1);
    stg(0, 0, 1, 1, 0); stg(0, 0, 1, 1, 1);
    stg(0, 0, 0, 0, 0); stg(0, 0, 0, 1, 0);
    stg(0, 0, 0, 0, 1); stg(0, 0, 0, 1, 1);
    VMCNT(2);                      // A.i1s may remain in flight (needed at p2)
    __builtin_amdgcn_s_barrier();

    const int NKT = K >> 6;
    for (int kt = 0; kt < NKT; ++kt) {
        const int cur  = (kt & 1) * 32768;
        const int nxtb = (kt & 1) ^ 1;
        const bool last = (kt == NKT - 1);
        bf16x8 bq[4][2];
        #pragma unroll
        for (int p = 0; p < 4; ++p) {
            bf16x8 af[2][2];
            if (p == 0) {
                #pragma unroll
                for (int n = 0; n < 4; ++n) {
                    bq[n][0] = *(const bf16x8*)&lds[cur + bbase + n * 1024 + arow + acol0];
                    bq[n][1] = *(const bf16x8*)&lds[cur + bbase + n * 1024 + arow + acol1];
                }
            }
            #pragma unroll
            for (int i = 0; i < 2; ++i) {
                af[i][0] = *(const bf16x8*)&lds[cur + abase + (2 * p + i) * 1024 + arow + acol0];
                af[i][1] = *(const bf16x8*)&lds[cur + abase + (2 * p + i) * 1024 + arow + acol1];
            }
            if (!last) {
                if (p == 0)      { stg(nxtb, kt + 1, 1, 0, 0); stg(nxtb, kt + 1, 1, 0, 1); }
                else if (p == 1) { stg(nxtb, kt + 1, 1, 1, 0); stg(nxtb, kt + 1, 1, 1, 1); }
                else if (p == 2) { stg(nxtb, kt + 1, 0, 0, 0); stg(nxtb, kt + 1, 0, 1, 0); }
                else             { stg(nxtb, kt + 1, 0, 0, 1); stg(nxtb, kt + 1, 0, 1, 1); }
            }
            if (p == 1) { if (last) { VMCNT(0); } else { VMCNT(4); } }
            if (p == 3 && !last) { VMCNT(2); }
            __builtin_amdgcn_s_barrier();
            __builtin_amdgcn_s_setprio(1);
            #pragma unroll
            for (int i = 0; i < 2; ++i)
                #pragma unroll
                for (int n = 0; n < 4; ++n) {
                    acc[2 * p + i][n] = __builtin_amdgcn_mfma_f32_16x16x32_bf16(af[i][0], bq[n][0], acc[2 * p + i][n], 0, 0, 0);
                    acc[2 * p + i][n] = __builtin_amdgcn_mfma_f32_16x16x32_bf16(af[i][1], bq[n][1], acc[2 * p + i][n], 0, 0, 0);
                }
            __builtin_amdgcn_s_setprio(0);
            __builtin_amdgcn_s_barrier();
        }
    }

    // epilogue
    const int cr0 = (lane >> 4) * 4;
    const int cc  = lr;
    #pragma unroll
    for (int m = 0; m < 8; ++m) {
        #pragma unroll
        for (int n = 0; n < 4; ++n) {
            #pragma unroll
            for (int r = 0; r < 4; ++r) {
                int row = bm + wr * 128 + m * 16 + cr0 + r;
                int col = bn + wc * 64 + n * 16 + cc;
                float v = acc[m][n][r];
                if (EPI == 0) {
                    if (col < D_INNER) {
                        bo0[(size_t)row * D_INNER + col] = f2bf(v);
                    } else {
                        float s = v / (1.f + __expf(-v));
                        bo1[(size_t)row * D_INNER + (col - D_INNER)] = f2bf(s);
                    }
                } else { // EPI == 3
                    fo0[(size_t)row * 1024 + col] = v + e0[(size_t)row * 1024 + col];
                }
            }
        }
    }
}

// ---------------- 128^2 prefetch-dbuf GEMM (for small-N/small-K gemms) ----------------
// EPI 1: x_proj (N=128 padded): fp32 xdbl[row*96+col] (col<96), bf16 dtin (col<64)
// EPI 2: dt:  softplus(acc + e0[col]) -> bf16 bo0[row*2048+col]
template<int EPI>
static __device__ __forceinline__ void gemm_core(
    const u16* __restrict__ A, const u16* __restrict__ B,
    int bm, int bn, int K,
    float* __restrict__ fo0, u16* __restrict__ bo0, u16* __restrict__ bo1,
    const float* __restrict__ e0)
{
    __shared__ u16 As[2][128 * 64];
    __shared__ u16 Bs[2][128 * 64];
    const int tid  = threadIdx.x;
    const int wid  = tid >> 6, lane = tid & 63;
    const int wm   = (wid >> 1) * 64, wn = (wid & 1) * 64;
    const int lr   = lane & 15, lk = (lane >> 4) * 8;

    const u16* Ag = A + (size_t)(bm + 32*wid + (lane >> 3)) * K + (lane & 7) * 8;
    const u16* Bg = B + (size_t)(bn + 32*wid + (lane >> 3)) * K + (lane & 7) * 8;
    const int lbase = wid * 2048;

    f32x4 acc[4][4];
    #pragma unroll
    for (int m = 0; m < 4; ++m)
        #pragma unroll
        for (int n = 0; n < 4; ++n)
            #pragma unroll
            for (int r = 0; r < 4; ++r) acc[m][n][r] = 0.f;

    auto stage = [&](int buf, int k0) {
        #pragma unroll
        for (int i = 0; i < 4; ++i) {
            gload16(Ag + (size_t)(8*i) * K + k0, &As[buf][lbase + i * 512]);
            gload16(Bg + (size_t)(8*i) * K + k0, &Bs[buf][lbase + i * 512]);
        }
    };

    const int nt = K >> 6;
    stage(0, 0);
    for (int t = 0; t < nt; ++t) {
        __syncthreads();
        if (t + 1 < nt) stage((t + 1) & 1, (t + 1) << 6);
        const int cb = t & 1;
        #pragma unroll
        for (int ks = 0; ks < 2; ++ks) {
            bf16x8 af[4], bfr[4];
            #pragma unroll
            for (int m = 0; m < 4; ++m)
                af[m] = *(const bf16x8*)&As[cb][(wm + m*16 + lr) * 64 + ks*32 + lk];
            #pragma unroll
            for (int n = 0; n < 4; ++n)
                bfr[n] = *(const bf16x8*)&Bs[cb][(wn + n*16 + lr) * 64 + ks*32 + lk];
            #pragma unroll
            for (int m = 0; m < 4; ++m)
                #pragma unroll
                for (int n = 0; n < 4; ++n)
                    acc[m][n] = __builtin_amdgcn_mfma_f32_16x16x32_bf16(af[m], bfr[n], acc[m][n], 0, 0, 0);
        }
    }

    const int cr0 = (lane >> 4) * 4;
    const int cc  = lane & 15;
    #pragma unroll
    for (int m = 0; m < 4; ++m) {
        #pragma unroll
        for (int n = 0; n < 4; ++n) {
            #pragma unroll
            for (int r = 0; r < 4; ++r) {
                int row = bm + wm + m*16 + cr0 + r;
                int col = bn + wn + n*16 + cc;
                float v = acc[m][n][r];
                if (EPI == 1) {
                    if (col < 96) fo0[(size_t)row * 96 + col] = v;
                    if (col < 64) bo0[(size_t)row * 64 + col] = f2bf(v);
                } else if (EPI == 2) {
                    float t2 = v + e0[col];
                    float sp = fmaxf(t2, 0.f) + __logf(1.f + __expf(-fabsf(t2)));
                    bo0[(size_t)row * D_INNER + col] = f2bf(sp);
                }
            }
        }
    }
}

__global__ __launch_bounds__(256) void gemm_xp(const u16* __restrict__ A, const u16* __restrict__ B,
                                               float* __restrict__ xdbl, u16* __restrict__ dtin) {
    gemm_core<1>(A, B, ((int)blockIdx.x) * 128, 0, 2048, xdbl, dtin, nullptr, nullptr);
}
__global__ __launch_bounds__(256) void gemm_dt(const u16* __restrict__ A, const u16* __restrict__ B,
                                               u16* __restrict__ dtb, const float* __restrict__ bias) {
    int q = 512 >> 3;
    int nb = (blockIdx.x & 7) * q + (blockIdx.x >> 3);
    int bm = nb >> 4, bn = nb & 15;
    gemm_core<2>(A, B, bm * 128, bn * 128, 64, nullptr, dtb, nullptr, bias);
}

// ---------------- depthwise causal conv(4) + bias + silu (8 d's / thread) ----------------
__global__ __launch_bounds__(256) void conv_silu(const u16* __restrict__ u,
                                                 const float* __restrict__ cw,
                                                 const float* __restrict__ cb,
                                                 u16* __restrict__ uc) {
    int tok = blockIdx.x;                        // 0..4095
    int d0  = threadIdx.x * 8;                   // 0..2040
    int t   = tok & (SEQ - 1);
    float acc[8];
    {
        float4 b0 = *(const float4*)&cb[d0];
        float4 b1 = *(const float4*)&cb[d0 + 4];
        acc[0]=b0.x; acc[1]=b0.y; acc[2]=b0.z; acc[3]=b0.w;
        acc[4]=b1.x; acc[5]=b1.y; acc[6]=b1.z; acc[7]=b1.w;
    }
    float4 c4[8];
    #pragma unroll
    for (int e = 0; e < 8; ++e) c4[e] = *(const float4*)&cw[(d0 + e) * 4];
    #pragma unroll
    for (int j = 0; j < 4; ++j) {
        int tt = t - 3 + j;
        if (tt < 0) continue;                    // uniform per block
        u16x8 uv = *(const u16x8*)&u[(size_t)(tok - 3 + j) * D_INNER + d0];
        const float* cj = (const float*)c4;
        #pragma unroll
        for (int e = 0; e < 8; ++e)
            acc[e] += bf2f(uv[e]) * cj[e * 4 + j];
    }
    u16x8 o;
    #pragma unroll
    for (int e = 0; e < 8; ++e) {
        float s = acc[e] / (1.f + __expf(-acc[e]));
        ((u16*)&o)[e] = f2bf(s);
    }
    *(u16x8*)&uc[(size_t)tok * D_INNER + d0] = o;
}

// ---------------- scan pass 1: per-chunk local end state + sum(dt) ----------------
__global__ __launch_bounds__(256) void scan1(const u16* __restrict__ dtb,
                                             const u16* __restrict__ uc,
                                             const float* __restrict__ xdbl,
                                             const float* __restrict__ A_log,
                                             float* __restrict__ hend,
                                             float* __restrict__ sdt_out) {
    int d = blockIdx.x * 256 + threadIdx.x;
    int c = blockIdx.y, b = blockIdx.z;
    float a2[NSTATE];
    #pragma unroll
    for (int n = 0; n < NSTATE; ++n)
        a2[n] = -__expf(A_log[d * NSTATE + n]) * LOG2E;
    float h[NSTATE];
    #pragma unroll
    for (int n = 0; n < NSTATE; ++n) h[n] = 0.f;
    float sdt = 0.f;
    int tok0 = b * SEQ + c * CHUNK;
    for (int t = 0; t < CHUNK; ++t) {
        int tok = tok0 + t;
        float dtv = bf2f(dtb[(size_t)tok * D_INNER + d]);
        float uv  = bf2f(uc[(size_t)tok * D_INNER + d]);
        float dtu = dtv * uv;
        const float4* Bp = (const float4*)(xdbl + (size_t)tok * 96 + 64);
        float4 B0 = Bp[0], B1 = Bp[1], B2 = Bp[2], B3 = Bp[3];
        float Bv[NSTATE] = {B0.x,B0.y,B0.z,B0.w, B1.x,B1.y,B1.z,B1.w,
                            B2.x,B2.y,B2.z,B2.w, B3.x,B3.y,B3.z,B3.w};
        sdt += dtv;
        #pragma unroll
        for (int n = 0; n < NSTATE; ++n) {
            float da = exp2f(a2[n] * dtv);
            h[n] = fmaf(da, h[n], dtu * Bv[n]);
        }
    }
    sdt_out[(size_t)(b * NCH + c) * D_INNER + d] = sdt;
    #pragma unroll
    for (int n = 0; n < NSTATE; ++n)
        hend[((size_t)(b * NCH + c) * NSTATE + n) * D_INNER + d] = h[n];
}

// ---------------- inter-chunk carry scan (in-place: hend -> carry-in) ----------------
__global__ __launch_bounds__(256) void scan_carry(float* __restrict__ hend,
                                                  const float* __restrict__ sdt,
                                                  const float* __restrict__ A_log) {
    int g = blockIdx.x * 256 + threadIdx.x;     // 65536
    int d = g & (D_INNER - 1);
    int n = (g >> 11) & (NSTATE - 1);
    int b = g >> 15;
    float a2 = -__expf(A_log[d * NSTATE + n]) * LOG2E;
    float H = 0.f;
    for (int c = 0; c < NCH; ++c) {
        size_t off = ((size_t)(b * NCH + c) * NSTATE + n) * D_INNER + d;
        float v = hend[off];
        float p = exp2f(a2 * sdt[(size_t)(b * NCH + c) * D_INNER + d]);
        hend[off] = H;                 // carry-in for chunk c
        H = fmaf(p, H, v);
    }
}

// ---------------- scan pass 2: full recurrence + Dskip + gate -> ys bf16 ----------------
__global__ __launch_bounds__(256) void scan2(const u16* __restrict__ dtb,
                                             const u16* __restrict__ uc,
                                             const float* __restrict__ xdbl,
                                             const float* __restrict__ A_log,
                                             const float* __restrict__ hin,
                                             const float* __restrict__ Dskip,
                                             const u16* __restrict__ zs,
                                             u16* __restrict__ ys) {
    int d = blockIdx.x * 256 + threadIdx.x;
    int c = blockIdx.y, b = blockIdx.z;
    float a2[NSTATE];
    #pragma unroll
    for (int n = 0; n < NSTATE; ++n)
        a2[n] = -__expf(A_log[d * NSTATE + n]) * LOG2E;
    float h[NSTATE];
    #pragma unroll
    for (int n = 0; n < NSTATE; ++n)
        h[n] = hin[((size_t)(b * NCH + c) * NSTATE + n) * D_INNER + d];
    float Dv = Dskip[d];
    int tok0 = b * SEQ + c * CHUNK;
    for (int t = 0; t < CHUNK; ++t) {
        int tok = tok0 + t;
        float dtv = bf2f(dtb[(size_t)tok * D_INNER + d]);
        float uv  = bf2f(uc[(size_t)tok * D_INNER + d]);
        float dtu = dtv * uv;
        const float4* Bp = (const float4*)(xdbl + (size_t)tok * 96 + 64);
        float4 B0 = Bp[0], B1 = Bp[1], B2 = Bp[2], B3 = Bp[3];
        const float4* Cp = (const float4*)(xdbl + (size_t)tok * 96 + 80);
        float4 C0 = Cp[0], C1 = Cp[1], C2 = Cp[2], C3 = Cp[3];
        float Bv[NSTATE] = {B0.x,B0.y,B0.z,B0.w, B1.x,B1.y,B1.z,B1.w,
                            B2.x,B2.y,B2.z,B2.w, B3.x,B3.y,B3.z,B3.w};
        float Cv[NSTATE] = {C0.x,C0.y,C0.z,C0.w, C1.x,C1.y,C1.z,C1.w,
                            C2.x,C2.y,C2.z,C2.w, C3.x,C3.y,C3.z,C3.w};
        float y = 0.f;
        #pragma unroll
        for (int n = 0; n < NSTATE; ++n) {
            float da = exp2f(a2[n] * dtv);
            h[n] = fmaf(da, h[n], dtu * Bv[n]);
            y = fmaf(h[n], Cv[n], y);
        }
        float g = bf2f(zs[(size_t)tok * D_INNER + d]);
        ys[(size_t)tok * D_INNER + d] = f2bf((y + uv * Dv) * g);
    }
}

// ---------------- host launcher ----------------
extern "C" void kernel_launch(void* const* d_in, const int* in_sizes, int n_in,
                              void* d_out, int out_size, void* d_ws, size_t ws_size,
                              hipStream_t stream) {
    const float* x        = (const float*)d_in[0];
    const float* ln_w     = (const float*)d_in[1];
    const float* ln_b     = (const float*)d_in[2];
    const float* in_projw = (const float*)d_in[3];
    const float* conv_w   = (const float*)d_in[4];
    const float* conv_b   = (const float*)d_in[5];
    const float* x_projw  = (const float*)d_in[6];
    const float* dt_projw = (const float*)d_in[7];
    const float* dt_projb = (const float*)d_in[8];
    const float* A_log    = (const float*)d_in[9];
    const float* Dskip    = (const float*)d_in[10];
    const float* out_projw= (const float*)d_in[11];
    float* out = (float*)d_out;

    uint8_t* w = (uint8_t*)d_ws;
    size_t off = 0;
    auto alloc = [&](size_t bytes) { uint8_t* p = w + off; off += (bytes + 255) & ~(size_t)255; return p; };

    u16* w1b   = (u16*)alloc((size_t)N_W1 * 2);
    u16* woutb = (u16*)alloc((size_t)N_WO * 2);
    u16* xpb   = (u16*)alloc((size_t)N_XPP * 2);   // padded to 128 rows
    u16* dtwb  = (u16*)alloc((size_t)N_DTW * 2);
    u16* y_bf  = (u16*)alloc((size_t)NTOK * 1024 * 2);
    u16* u_bf  = (u16*)alloc((size_t)NTOK * 2048 * 2);   // reused as ys_bf after conv
    u16* zs_bf = (u16*)alloc((size_t)NTOK * 2048 * 2);
    u16* uc_bf = (u16*)alloc((size_t)NTOK * 2048 * 2);
    float* xdbl  = (float*)alloc((size_t)NTOK * 96 * 4);
    u16*   dtinb = (u16*)alloc((size_t)NTOK * 64 * 2);
    u16*   dt_bf = (u16*)alloc((size_t)NTOK * 2048 * 2);
    float* sdt   = (float*)alloc((size_t)BATCH * NCH * 2048 * 4);
    float* hend  = (float*)alloc((size_t)BATCH * NCH * NSTATE * 2048 * 4);
    u16* ys_bf = u_bf;
    (void)ws_size; (void)n_in; (void)in_sizes; (void)out_size;

    // fused weight casts (+ x_proj zero-pad)
    cast_weights<<<2048, 256, 0, stream>>>(in_projw, out_projw, x_projw, dt_projw,
                                           w1b, woutb, xpb, dtwb);

    // LayerNorm -> bf16
    ln_cast<<<NTOK, 256, 0, stream>>>(x, ln_w, ln_b, y_bf);

    // in_proj: [4096,1024] x [4096,1024]^T -> split u / silu(z)   (256^2 pipelined)
    gemm256<0, 1024, 16, 256><<<256, 512, 0, stream>>>(y_bf, w1b, nullptr, u_bf, zs_bf, nullptr);

    // conv + silu
    conv_silu<<<NTOK, 256, 0, stream>>>(u_bf, conv_w, conv_b, uc_bf);

    // x_proj: [4096,2048] x [128(pad),2048]^T -> xdbl fp32 + dt-input bf16
    gemm_xp<<<32, 256, 0, stream>>>(uc_bf, xpb, xdbl, dtinb);
    // dt_proj + softplus -> bf16: [4096,64] x [2048,64]^T
    gemm_dt<<<512, 256, 0, stream>>>(dtinb, dtwb, dt_bf, dt_projb);

    // chunked selective scan
    scan1<<<dim3(8, NCH, BATCH), 256, 0, stream>>>(dt_bf, uc_bf, xdbl, A_log, hend, sdt);
    scan_carry<<<256, 256, 0, stream>>>(hend, sdt, A_log);
    scan2<<<dim3(8, NCH, BATCH), 256, 0, stream>>>(dt_bf, uc_bf, xdbl, A_log, hend, Dskip, zs_bf, ys_bf);

    // out_proj + residual   (256^2 pipelined)
    gemm256<3, 2048, 4, 64><<<64, 512, 0, stream>>>(ys_bf, woutb, out, nullptr, nullptr, x);
}

// Round 5
// 280.583 us; speedup vs baseline: 1.7940x; 1.1291x over previous
//
#include <hip/hip_runtime.h>
#include <cstdint>
#include <cstddef>

typedef unsigned short u16;
typedef __attribute__((ext_vector_type(8))) __bf16 bf16x8;
typedef __attribute__((ext_vector_type(8))) u16   u16x8;
typedef __attribute__((ext_vector_type(4))) float f32x4;

#define D_MODEL 1024
#define D_INNER 2048
#define NSTATE  16
#define DT_RANK 64
#define BATCH   2
#define SEQ     2048
#define NTOK    (BATCH*SEQ)      // 4096
#define CHUNK   64
#define NCH     (SEQ/CHUNK)      // 32
#define LOG2E   1.44269504088896340736f

#define VMCNT(n) asm volatile("s_waitcnt vmcnt(" #n ")" ::: "memory")

static __device__ __forceinline__ u16 f2bf(float f) {
    uint32_t u = __builtin_bit_cast(uint32_t, f);
    u += 0x7fffu + ((u >> 16) & 1u);          // RNE
    return (u16)(u >> 16);
}
static __device__ __forceinline__ float bf2f(u16 h) {
    uint32_t u = ((uint32_t)h) << 16;
    return __builtin_bit_cast(float, u);
}

// async global->LDS, 16B per lane; lds dest is wave-uniform base + lane*16
static __device__ __forceinline__ void gload16(const u16* g, u16* l) {
    __builtin_amdgcn_global_load_lds(
        (const __attribute__((address_space(1))) void*)g,
        (__attribute__((address_space(3))) void*)l, 16, 0, 0);
}

// ---------------- fused weight casts (+ zero-pad x_proj to 128 rows) ----------------
#define N_W1  (4096*1024)
#define N_WO  (1024*2048)
#define N_XP  (96*2048)
#define N_XPP (128*2048)
#define N_DTW (2048*64)
#define N_ALL (N_W1 + N_WO + N_XPP + N_DTW)

__global__ __launch_bounds__(256) void cast_weights(
    const float* __restrict__ w1, const float* __restrict__ wo,
    const float* __restrict__ xp, const float* __restrict__ dtw,
    u16* __restrict__ o1, u16* __restrict__ oo,
    u16* __restrict__ oxp, u16* __restrict__ odt)
{
    int i = (blockIdx.x * 256 + threadIdx.x) * 4;
    int stride = gridDim.x * 256 * 4;
    for (; i < N_ALL; i += stride) {
        const float* src; u16* dst; int off;
        if (i < N_W1)                { src = w1;  dst = o1;  off = i; }
        else if (i < N_W1 + N_WO)    { src = wo;  dst = oo;  off = i - N_W1; }
        else if (i < N_W1 + N_WO + N_XPP) {
            off = i - N_W1 - N_WO; dst = oxp;
            if (off >= N_XP) { ushort4 z = {0,0,0,0}; *(ushort4*)&oxp[off] = z; continue; }
            src = xp;
        } else                       { src = dtw; dst = odt; off = i - N_W1 - N_WO - N_XPP; }
        float4 v = *(const float4*)&src[off];
        ushort4 o4;
        o4.x = f2bf(v.x); o4.y = f2bf(v.y); o4.z = f2bf(v.z); o4.w = f2bf(v.w);
        *(ushort4*)&dst[off] = o4;
    }
}

// ---------------- LayerNorm + bf16 cast ----------------
__global__ __launch_bounds__(256) void ln_cast(const float* __restrict__ x,
                                               const float* __restrict__ w,
                                               const float* __restrict__ bb,
                                               u16* __restrict__ y) {
    int row = blockIdx.x;
    const float4 v = ((const float4*)(x + (size_t)row * D_MODEL))[threadIdx.x];
    float s  = v.x + v.y + v.z + v.w;
    float sq = v.x*v.x + v.y*v.y + v.z*v.z + v.w*v.w;
    #pragma unroll
    for (int o = 32; o > 0; o >>= 1) {
        s  += __shfl_down(s,  o, 64);
        sq += __shfl_down(sq, o, 64);
    }
    __shared__ float sh[8];
    int wv = threadIdx.x >> 6;
    if ((threadIdx.x & 63) == 0) { sh[wv] = s; sh[4 + wv] = sq; }
    __syncthreads();
    s  = sh[0] + sh[1] + sh[2] + sh[3];
    sq = sh[4] + sh[5] + sh[6] + sh[7];
    float mu  = s * (1.f / D_MODEL);
    float var = sq * (1.f / D_MODEL) - mu * mu;
    float inv = rsqrtf(var + 1e-5f);
    int c = threadIdx.x * 4;
    ushort4 o4;
    o4.x = f2bf((v.x - mu) * inv * w[c+0] + bb[c+0]);
    o4.y = f2bf((v.y - mu) * inv * w[c+1] + bb[c+1]);
    o4.z = f2bf((v.z - mu) * inv * w[c+2] + bb[c+2]);
    o4.w = f2bf((v.w - mu) * inv * w[c+3] + bb[c+3]);
    ((ushort4*)(y + (size_t)row * D_MODEL))[threadIdx.x] = o4;
}

// ================= 256x256 8-wave phase-pipelined bf16 GEMM =================
// C[M,N] = A[M,K] * B[N,K]^T.  512 thr = 8 waves (2 wr x 4 wc), per-wave 128x64.
// Strict double-buffer; ALL 8 loads for kt+1 issued at p0 of kt (after the
// end-of-kt-1 barrier closed all reads of that buffer).  Counted waits:
//   VMCNT(8)@p1: completes kt's A-j1 (issued p0 of kt-1, 5 phases earlier)
//   VMCNT(2)@p3: completes kt+1's B + A-j0 (issued p0 of kt, 3 phases earlier)
// XOR swizzle (16B chunk ^ (row&7)) via pre-swizzled global source + swizzled
// ds_read (rule #21).  EPI 0: split u/z.  EPI 3: out = acc + resid.
template<int EPI, int K, int NTN, int NWG>
__global__ __launch_bounds__(512, 2) void gemm256(
    const u16* __restrict__ A, const u16* __restrict__ B,
    float* __restrict__ fo0, u16* __restrict__ bo0, u16* __restrict__ bo1,
    const float* __restrict__ e0)
{
    __shared__ u16 lds[65536];   // 128 KB
    const int tid = threadIdx.x, wid = tid >> 6, lane = tid & 63;
    const int wr = wid >> 2, wc = wid & 3, lr = lane & 15;
    // bijective XCD swizzle (NWG % 8 == 0)
    const int nb = (blockIdx.x & 7) * (NWG >> 3) + (blockIdx.x >> 3);
    const int bm = (nb / NTN) * 256, bn = (nb % NTN) * 256;

    const int srow = wid * 8 + (lane >> 3);
    const int scol = 8 * ((lane & 7) ^ ((lane >> 3) & 7));   // pre-swizzled source col
    const u16* Asrc = A + (size_t)(bm + srow) * K + scol;
    const u16* Bsrc = B + (size_t)(bn + srow) * K + scol;
    const int dwave = wid * 512;

    auto stg = [&](int buf, int kt, int mat, int half, int j) {
        gload16((mat ? Bsrc : Asrc) + (size_t)(half * 128 + j * 64) * K + kt * 64,
                &lds[buf * 32768 + mat * 16384 + half * 8192 + j * 4096 + dwave]);
    };
    // order: 4xB, A-j0 (h0,h1), A-j1 (h0,h1) -> vmcnt(2) leaves exactly A-j1
    auto issue8 = [&](int buf, int kt) {
        stg(buf, kt, 1, 0, 0); stg(buf, kt, 1, 0, 1);
        stg(buf, kt, 1, 1, 0); stg(buf, kt, 1, 1, 1);
        stg(buf, kt, 0, 0, 0); stg(buf, kt, 0, 1, 0);
        stg(buf, kt, 0, 0, 1); stg(buf, kt, 0, 1, 1);
    };

    // ds_read addressing (elem units), swizzled chunk: (chunkidx ^ (row&7)) * 8
    const int key   = (lr & 7) << 4;
    const int acol0 = (((lane >> 4) * 16) ^ key) >> 1;
    const int acol1 = ((64 | ((lane >> 4) * 16)) ^ key) >> 1;
    const int arow  = lr * 64;
    const int abase = wr * 8192;
    const int bbase = 16384 + (wc >> 1) * 8192 + (wc & 1) * 4096;

    f32x4 acc[8][4];
    #pragma unroll
    for (int m = 0; m < 8; ++m)
        #pragma unroll
        for (int n = 0; n < 4; ++n)
            #pragma unroll
            for (int r = 0; r < 4; ++r) acc[m][n][r] = 0.f;

    // prologue
    issue8(0, 0);
    VMCNT(2);
    __builtin_amdgcn_s_barrier();

    const int NKT = K >> 6;
    for (int kt = 0; kt < NKT; ++kt) {
        const int cur  = (kt & 1) * 32768;
        const bool last = (kt == NKT - 1);
        bf16x8 bq[4][2];
        #pragma unroll
        for (int p = 0; p < 4; ++p) {
            bf16x8 af[2][2];
            if (p == 0) {
                #pragma unroll
                for (int n = 0; n < 4; ++n) {
                    bq[n][0] = *(const bf16x8*)&lds[cur + bbase + n * 1024 + arow + acol0];
                    bq[n][1] = *(const bf16x8*)&lds[cur + bbase + n * 1024 + arow + acol1];
                }
            }
            #pragma unroll
            for (int i = 0; i < 2; ++i) {
                af[i][0] = *(const bf16x8*)&lds[cur + abase + (2 * p + i) * 1024 + arow + acol0];
                af[i][1] = *(const bf16x8*)&lds[cur + abase + (2 * p + i) * 1024 + arow + acol1];
            }
            if (p == 0 && !last) issue8((kt & 1) ^ 1, kt + 1);
            if (p == 1) { if (last) { VMCNT(0); } else { VMCNT(8); } }
            if (p == 3 && !last) { VMCNT(2); }
            __builtin_amdgcn_s_barrier();
            asm volatile("s_waitcnt lgkmcnt(0)" ::: "memory");
            __builtin_amdgcn_sched_barrier(0);
            __builtin_amdgcn_s_setprio(1);
            #pragma unroll
            for (int i = 0; i < 2; ++i)
                #pragma unroll
                for (int n = 0; n < 4; ++n) {
                    acc[2 * p + i][n] = __builtin_amdgcn_mfma_f32_16x16x32_bf16(af[i][0], bq[n][0], acc[2 * p + i][n], 0, 0, 0);
                    acc[2 * p + i][n] = __builtin_amdgcn_mfma_f32_16x16x32_bf16(af[i][1], bq[n][1], acc[2 * p + i][n], 0, 0, 0);
                }
            __builtin_amdgcn_s_setprio(0);
            __builtin_amdgcn_s_barrier();
        }
    }

    // epilogue
    const int cr0 = (lane >> 4) * 4;
    const int cc  = lr;
    #pragma unroll
    for (int m = 0; m < 8; ++m) {
        #pragma unroll
        for (int n = 0; n < 4; ++n) {
            #pragma unroll
            for (int r = 0; r < 4; ++r) {
                int row = bm + wr * 128 + m * 16 + cr0 + r;
                int col = bn + wc * 64 + n * 16 + cc;
                float v = acc[m][n][r];
                if (EPI == 0) {
                    if (col < D_INNER) {
                        bo0[(size_t)row * D_INNER + col] = f2bf(v);
                    } else {
                        float s = v / (1.f + __expf(-v));
                        bo1[(size_t)row * D_INNER + (col - D_INNER)] = f2bf(s);
                    }
                } else { // EPI == 3
                    fo0[(size_t)row * 1024 + col] = v + e0[(size_t)row * 1024 + col];
                }
            }
        }
    }
}

// ---------------- 128^2 prefetch-dbuf GEMM (small-N/small-K / split-K) ----------------
// EPI 1: split-K partial: fp32 fo0[row*96+col] (col<96)
// EPI 2: dt:  softplus(acc + e0[col]) -> bf16 bo0[row*2048+col]
template<int EPI>
static __device__ __forceinline__ void gemm_core(
    const u16* __restrict__ A, const u16* __restrict__ B,
    int bm, int bn, int kbeg, int klen, int lda,
    float* __restrict__ fo0, u16* __restrict__ bo0,
    const float* __restrict__ e0)
{
    __shared__ u16 As[2][128 * 64];
    __shared__ u16 Bs[2][128 * 64];
    const int tid  = threadIdx.x;
    const int wid  = tid >> 6, lane = tid & 63;
    const int wm   = (wid >> 1) * 64, wn = (wid & 1) * 64;
    const int lr   = lane & 15, lk = (lane >> 4) * 8;

    const u16* Ag = A + (size_t)(bm + 32*wid + (lane >> 3)) * lda + kbeg + (lane & 7) * 8;
    const u16* Bg = B + (size_t)(bn + 32*wid + (lane >> 3)) * lda + kbeg + (lane & 7) * 8;
    const int lbase = wid * 2048;

    f32x4 acc[4][4];
    #pragma unroll
    for (int m = 0; m < 4; ++m)
        #pragma unroll
        for (int n = 0; n < 4; ++n)
            #pragma unroll
            for (int r = 0; r < 4; ++r) acc[m][n][r] = 0.f;

    auto stage = [&](int buf, int k0) {
        #pragma unroll
        for (int i = 0; i < 4; ++i) {
            gload16(Ag + (size_t)(8*i) * lda + k0, &As[buf][lbase + i * 512]);
            gload16(Bg + (size_t)(8*i) * lda + k0, &Bs[buf][lbase + i * 512]);
        }
    };

    const int nt = klen >> 6;
    stage(0, 0);
    for (int t = 0; t < nt; ++t) {
        __syncthreads();
        if (t + 1 < nt) stage((t + 1) & 1, (t + 1) << 6);
        const int cb = t & 1;
        #pragma unroll
        for (int ks = 0; ks < 2; ++ks) {
            bf16x8 af[4], bfr[4];
            #pragma unroll
            for (int m = 0; m < 4; ++m)
                af[m] = *(const bf16x8*)&As[cb][(wm + m*16 + lr) * 64 + ks*32 + lk];
            #pragma unroll
            for (int n = 0; n < 4; ++n)
                bfr[n] = *(const bf16x8*)&Bs[cb][(wn + n*16 + lr) * 64 + ks*32 + lk];
            #pragma unroll
            for (int m = 0; m < 4; ++m)
                #pragma unroll
                for (int n = 0; n < 4; ++n)
                    acc[m][n] = __builtin_amdgcn_mfma_f32_16x16x32_bf16(af[m], bfr[n], acc[m][n], 0, 0, 0);
        }
    }

    const int cr0 = (lane >> 4) * 4;
    const int cc  = lane & 15;
    #pragma unroll
    for (int m = 0; m < 4; ++m) {
        #pragma unroll
        for (int n = 0; n < 4; ++n) {
            #pragma unroll
            for (int r = 0; r < 4; ++r) {
                int row = bm + wm + m*16 + cr0 + r;
                int col = bn + wn + n*16 + cc;
                float v = acc[m][n][r];
                if (EPI == 1) {
                    if (col < 96) fo0[(size_t)row * 96 + col] = v;
                } else if (EPI == 2) {
                    float t2 = v + e0[col];
                    float sp = fmaxf(t2, 0.f) + __logf(1.f + __expf(-fabsf(t2)));
                    bo0[(size_t)row * D_INNER + col] = f2bf(sp);
                }
            }
        }
    }
}

// x_proj split-K: grid 32 m-tiles x 8 splits; partial fp32 -> psum[s][4096][96]
__global__ __launch_bounds__(256) void gemm_xp(const u16* __restrict__ A, const u16* __restrict__ B,
                                               float* __restrict__ psum) {
    int bm = blockIdx.x >> 3;
    int s  = blockIdx.x & 7;
    gemm_core<1>(A, B, bm * 128, 0, s * 256, 256, 2048,
                 psum + (size_t)s * 4096 * 96, nullptr, nullptr);
}
// reduce 8 partials -> xdbl fp32 + dtin bf16
__global__ __launch_bounds__(256) void xp_reduce(const float* __restrict__ psum,
                                                 float* __restrict__ xdbl,
                                                 u16* __restrict__ dtinb) {
    int t = blockIdx.x * 256 + threadIdx.x;      // 4096*24 = 98304
    int row = t / 24, c4 = (t - row * 24) * 4;
    float4 s = {0.f, 0.f, 0.f, 0.f};
    #pragma unroll
    for (int k = 0; k < 8; ++k) {
        float4 v = *(const float4*)&psum[(size_t)k * 4096 * 96 + (size_t)row * 96 + c4];
        s.x += v.x; s.y += v.y; s.z += v.z; s.w += v.w;
    }
    *(float4*)&xdbl[(size_t)row * 96 + c4] = s;
    if (c4 < 64) {
        ushort4 o4;
        o4.x = f2bf(s.x); o4.y = f2bf(s.y); o4.z = f2bf(s.z); o4.w = f2bf(s.w);
        *(ushort4*)&dtinb[(size_t)row * 64 + c4] = o4;
    }
}

__global__ __launch_bounds__(256) void gemm_dt(const u16* __restrict__ A, const u16* __restrict__ B,
                                               u16* __restrict__ dtb, const float* __restrict__ bias) {
    int q = 512 >> 3;
    int nb = (blockIdx.x & 7) * q + (blockIdx.x >> 3);
    int bm = nb >> 4, bn = nb & 15;
    gemm_core<2>(A, B, bm * 128, bn * 128, 0, 64, 64, nullptr, dtb, bias);
}

// ---------------- depthwise causal conv(4) + bias + silu (8 d's / thread) ----------------
__global__ __launch_bounds__(256) void conv_silu(const u16* __restrict__ u,
                                                 const float* __restrict__ cw,
                                                 const float* __restrict__ cb,
                                                 u16* __restrict__ uc) {
    int tok = blockIdx.x;                        // 0..4095
    int d0  = threadIdx.x * 8;                   // 0..2040
    int t   = tok & (SEQ - 1);
    float acc[8];
    {
        float4 b0 = *(const float4*)&cb[d0];
        float4 b1 = *(const float4*)&cb[d0 + 4];
        acc[0]=b0.x; acc[1]=b0.y; acc[2]=b0.z; acc[3]=b0.w;
        acc[4]=b1.x; acc[5]=b1.y; acc[6]=b1.z; acc[7]=b1.w;
    }
    float4 c4[8];
    #pragma unroll
    for (int e = 0; e < 8; ++e) c4[e] = *(const float4*)&cw[(d0 + e) * 4];
    #pragma unroll
    for (int j = 0; j < 4; ++j) {
        int tt = t - 3 + j;
        if (tt < 0) continue;                    // uniform per block
        u16x8 uv = *(const u16x8*)&u[(size_t)(tok - 3 + j) * D_INNER + d0];
        const float* cj = (const float*)c4;
        #pragma unroll
        for (int e = 0; e < 8; ++e)
            acc[e] += bf2f(uv[e]) * cj[e * 4 + j];
    }
    u16x8 o;
    #pragma unroll
    for (int e = 0; e < 8; ++e) {
        float s = acc[e] / (1.f + __expf(-acc[e]));
        ((u16*)&o)[e] = f2bf(s);
    }
    *(u16x8*)&uc[(size_t)tok * D_INNER + d0] = o;
}

// ---------------- scan pass 1: per-chunk local end state + sum(dt) ----------------
__global__ __launch_bounds__(256) void scan1(const u16* __restrict__ dtb,
                                             const u16* __restrict__ uc,
                                             const float* __restrict__ xdbl,
                                             const float* __restrict__ A_log,
                                             float* __restrict__ hend,
                                             float* __restrict__ sdt_out) {
    int d = blockIdx.x * 256 + threadIdx.x;
    int c = blockIdx.y, b = blockIdx.z;
    float a2[NSTATE];
    #pragma unroll
    for (int n = 0; n < NSTATE; ++n)
        a2[n] = -__expf(A_log[d * NSTATE + n]) * LOG2E;
    float h[NSTATE];
    #pragma unroll
    for (int n = 0; n < NSTATE; ++n) h[n] = 0.f;
    float sdt = 0.f;
    int tok0 = b * SEQ + c * CHUNK;
    for (int t = 0; t < CHUNK; ++t) {
        int tok = tok0 + t;
        float dtv = bf2f(dtb[(size_t)tok * D_INNER + d]);
        float uv  = bf2f(uc[(size_t)tok * D_INNER + d]);
        float dtu = dtv * uv;
        const float4* Bp = (const float4*)(xdbl + (size_t)tok * 96 + 64);
        float4 B0 = Bp[0], B1 = Bp[1], B2 = Bp[2], B3 = Bp[3];
        float Bv[NSTATE] = {B0.x,B0.y,B0.z,B0.w, B1.x,B1.y,B1.z,B1.w,
                            B2.x,B2.y,B2.z,B2.w, B3.x,B3.y,B3.z,B3.w};
        sdt += dtv;
        #pragma unroll
        for (int n = 0; n < NSTATE; ++n) {
            float da = exp2f(a2[n] * dtv);
            h[n] = fmaf(da, h[n], dtu * Bv[n]);
        }
    }
    sdt_out[(size_t)(b * NCH + c) * D_INNER + d] = sdt;
    #pragma unroll
    for (int n = 0; n < NSTATE; ++n)
        hend[((size_t)(b * NCH + c) * NSTATE + n) * D_INNER + d] = h[n];
}

// ---------------- inter-chunk carry scan (in-place: hend -> carry-in) ----------------
__global__ __launch_bounds__(256) void scan_carry(float* __restrict__ hend,
                                                  const float* __restrict__ sdt,
                                                  const float* __restrict__ A_log) {
    int g = blockIdx.x * 256 + threadIdx.x;     // 65536
    int d = g & (D_INNER - 1);
    int n = (g >> 11) & (NSTATE - 1);
    int b = g >> 15;
    float a2 = -__expf(A_log[d * NSTATE + n]) * LOG2E;
    float H = 0.f;
    for (int c = 0; c < NCH; ++c) {
        size_t off = ((size_t)(b * NCH + c) * NSTATE + n) * D_INNER + d;
        float v = hend[off];
        float p = exp2f(a2 * sdt[(size_t)(b * NCH + c) * D_INNER + d]);
        hend[off] = H;                 // carry-in for chunk c
        H = fmaf(p, H, v);
    }
}

// ---------------- scan pass 2: full recurrence + Dskip + gate -> ys bf16 ----------------
__global__ __launch_bounds__(256) void scan2(const u16* __restrict__ dtb,
                                             const u16* __restrict__ uc,
                                             const float* __restrict__ xdbl,
                                             const float* __restrict__ A_log,
                                             const float* __restrict__ hin,
                                             const float* __restrict__ Dskip,
                                             const u16* __restrict__ zs,
                                             u16* __restrict__ ys) {
    int d = blockIdx.x * 256 + threadIdx.x;
    int c = blockIdx.y, b = blockIdx.z;
    float a2[NSTATE];
    #pragma unroll
    for (int n = 0; n < NSTATE; ++n)
        a2[n] = -__expf(A_log[d * NSTATE + n]) * LOG2E;
    float h[NSTATE];
    #pragma unroll
    for (int n = 0; n < NSTATE; ++n)
        h[n] = hin[((size_t)(b * NCH + c) * NSTATE + n) * D_INNER + d];
    float Dv = Dskip[d];
    int tok0 = b * SEQ + c * CHUNK;
    for (int t = 0; t < CHUNK; ++t) {
        int tok = tok0 + t;
        float dtv = bf2f(dtb[(size_t)tok * D_INNER + d]);
        float uv  = bf2f(uc[(size_t)tok * D_INNER + d]);
        float dtu = dtv * uv;
        const float4* Bp = (const float4*)(xdbl + (size_t)tok * 96 + 64);
        float4 B0 = Bp[0], B1 = Bp[1], B2 = Bp[2], B3 = Bp[3];
        const float4* Cp = (const float4*)(xdbl + (size_t)tok * 96 + 80);
        float4 C0 = Cp[0], C1 = Cp[1], C2 = Cp[2], C3 = Cp[3];
        float Bv[NSTATE] = {B0.x,B0.y,B0.z,B0.w, B1.x,B1.y,B1.z,B1.w,
                            B2.x,B2.y,B2.z,B2.w, B3.x,B3.y,B3.z,B3.w};
        float Cv[NSTATE] = {C0.x,C0.y,C0.z,C0.w, C1.x,C1.y,C1.z,C1.w,
                            C2.x,C2.y,C2.z,C2.w, C3.x,C3.y,C3.z,C3.w};
        float y = 0.f;
        #pragma unroll
        for (int n = 0; n < NSTATE; ++n) {
            float da = exp2f(a2[n] * dtv);
            h[n] = fmaf(da, h[n], dtu * Bv[n]);
            y = fmaf(h[n], Cv[n], y);
        }
        float g = bf2f(zs[(size_t)tok * D_INNER + d]);
        ys[(size_t)tok * D_INNER + d] = f2bf((y + uv * Dv) * g);
    }
}

// ---------------- host launcher ----------------
extern "C" void kernel_launch(void* const* d_in, const int* in_sizes, int n_in,
                              void* d_out, int out_size, void* d_ws, size_t ws_size,
                              hipStream_t stream) {
    const float* x        = (const float*)d_in[0];
    const float* ln_w     = (const float*)d_in[1];
    const float* ln_b     = (const float*)d_in[2];
    const float* in_projw = (const float*)d_in[3];
    const float* conv_w   = (const float*)d_in[4];
    const float* conv_b   = (const float*)d_in[5];
    const float* x_projw  = (const float*)d_in[6];
    const float* dt_projw = (const float*)d_in[7];
    const float* dt_projb = (const float*)d_in[8];
    const float* A_log    = (const float*)d_in[9];
    const float* Dskip    = (const float*)d_in[10];
    const float* out_projw= (const float*)d_in[11];
    float* out = (float*)d_out;

    uint8_t* w = (uint8_t*)d_ws;
    size_t off = 0;
    auto alloc = [&](size_t bytes) { uint8_t* p = w + off; off += (bytes + 255) & ~(size_t)255; return p; };

    u16* w1b   = (u16*)alloc((size_t)N_W1 * 2);
    u16* woutb = (u16*)alloc((size_t)N_WO * 2);
    u16* xpb   = (u16*)alloc((size_t)N_XPP * 2);   // padded to 128 rows
    u16* dtwb  = (u16*)alloc((size_t)N_DTW * 2);
    u16* y_bf  = (u16*)alloc((size_t)NTOK * 1024 * 2);
    u16* u_bf  = (u16*)alloc((size_t)NTOK * 2048 * 2);   // reused as ys_bf after conv
    u16* zs_bf = (u16*)alloc((size_t)NTOK * 2048 * 2);
    u16* uc_bf = (u16*)alloc((size_t)NTOK * 2048 * 2);
    float* xdbl  = (float*)alloc((size_t)NTOK * 96 * 4);
    u16*   dtinb = (u16*)alloc((size_t)NTOK * 64 * 2);
    u16*   dt_bf = (u16*)alloc((size_t)NTOK * 2048 * 2);
    float* sdt   = (float*)alloc((size_t)BATCH * NCH * 2048 * 4);
    float* hend  = (float*)alloc((size_t)BATCH * NCH * NSTATE * 2048 * 4);
    float* psum  = (float*)alloc((size_t)8 * 4096 * 96 * 4);
    u16* ys_bf = u_bf;
    (void)ws_size; (void)n_in; (void)in_sizes; (void)out_size;

    // fused weight casts (+ x_proj zero-pad)
    cast_weights<<<2048, 256, 0, stream>>>(in_projw, out_projw, x_projw, dt_projw,
                                           w1b, woutb, xpb, dtwb);

    // LayerNorm -> bf16
    ln_cast<<<NTOK, 256, 0, stream>>>(x, ln_w, ln_b, y_bf);

    // in_proj: [4096,1024] x [4096,1024]^T -> split u / silu(z)   (256^2 pipelined)
    gemm256<0, 1024, 16, 256><<<256, 512, 0, stream>>>(y_bf, w1b, nullptr, u_bf, zs_bf, nullptr);

    // conv + silu
    conv_silu<<<NTOK, 256, 0, stream>>>(u_bf, conv_w, conv_b, uc_bf);

    // x_proj split-K: [4096,2048] x [128(pad),2048]^T -> 8 partials -> reduce
    gemm_xp<<<256, 256, 0, stream>>>(uc_bf, xpb, psum);
    xp_reduce<<<384, 256, 0, stream>>>(psum, xdbl, dtinb);

    // dt_proj + softplus -> bf16: [4096,64] x [2048,64]^T
    gemm_dt<<<512, 256, 0, stream>>>(dtinb, dtwb, dt_bf, dt_projb);

    // chunked selective scan
    scan1<<<dim3(8, NCH, BATCH), 256, 0, stream>>>(dt_bf, uc_bf, xdbl, A_log, hend, sdt);
    scan_carry<<<256, 256, 0, stream>>>(hend, sdt, A_log);
    scan2<<<dim3(8, NCH, BATCH), 256, 0, stream>>>(dt_bf, uc_bf, xdbl, A_log, hend, Dskip, zs_bf, ys_bf);

    // out_proj + residual   (256^2 pipelined)
    gemm256<3, 2048, 4, 64><<<64, 512, 0, stream>>>(ys_bf, woutb, out, nullptr, nullptr, x);
}

// Round 6
// 238.635 us; speedup vs baseline: 2.1094x; 1.1758x over previous
//
#include <hip/hip_runtime.h>
#include <cstdint>
#include <cstddef>

typedef unsigned short u16;
typedef __attribute__((ext_vector_type(8))) __bf16 bf16x8;
typedef __attribute__((ext_vector_type(8))) u16   u16x8;
typedef __attribute__((ext_vector_type(4))) float f32x4;

#define D_MODEL 1024
#define D_INNER 2048
#define NSTATE  16
#define DT_RANK 64
#define BATCH   2
#define SEQ     2048
#define NTOK    (BATCH*SEQ)      // 4096
#define CHUNK   64
#define NCH     (SEQ/CHUNK)      // 32
#define LOG2E   1.44269504088896340736f

#define VMCNT0() asm volatile("s_waitcnt vmcnt(0)" ::: "memory")

static __device__ __forceinline__ u16 f2bf(float f) {
    uint32_t u = __builtin_bit_cast(uint32_t, f);
    u += 0x7fffu + ((u >> 16) & 1u);          // RNE
    return (u16)(u >> 16);
}
static __device__ __forceinline__ float bf2f(u16 h) {
    uint32_t u = ((uint32_t)h) << 16;
    return __builtin_bit_cast(float, u);
}

// async global->LDS, 16B per lane; lds dest is wave-uniform base + lane*16
static __device__ __forceinline__ void gload16(const u16* g, u16* l) {
    __builtin_amdgcn_global_load_lds(
        (const __attribute__((address_space(1))) void*)g,
        (__attribute__((address_space(3))) void*)l, 16, 0, 0);
}

// ---------------- fused weight casts (+ zero-pad x_proj to 128 rows) ----------------
#define N_W1  (4096*1024)
#define N_WO  (1024*2048)
#define N_XP  (96*2048)
#define N_XPP (128*2048)
#define N_DTW (2048*64)
#define N_ALL (N_W1 + N_WO + N_XPP + N_DTW)

__global__ __launch_bounds__(256) void cast_weights(
    const float* __restrict__ w1, const float* __restrict__ wo,
    const float* __restrict__ xp, const float* __restrict__ dtw,
    u16* __restrict__ o1, u16* __restrict__ oo,
    u16* __restrict__ oxp, u16* __restrict__ odt)
{
    int i = (blockIdx.x * 256 + threadIdx.x) * 4;
    int stride = gridDim.x * 256 * 4;
    for (; i < N_ALL; i += stride) {
        const float* src; u16* dst; int off;
        if (i < N_W1)                { src = w1;  dst = o1;  off = i; }
        else if (i < N_W1 + N_WO)    { src = wo;  dst = oo;  off = i - N_W1; }
        else if (i < N_W1 + N_WO + N_XPP) {
            off = i - N_W1 - N_WO; dst = oxp;
            if (off >= N_XP) { ushort4 z = {0,0,0,0}; *(ushort4*)&oxp[off] = z; continue; }
            src = xp;
        } else                       { src = dtw; dst = odt; off = i - N_W1 - N_WO - N_XPP; }
        float4 v = *(const float4*)&src[off];
        ushort4 o4;
        o4.x = f2bf(v.x); o4.y = f2bf(v.y); o4.z = f2bf(v.z); o4.w = f2bf(v.w);
        *(ushort4*)&dst[off] = o4;
    }
}

// ---------------- LayerNorm + bf16 cast ----------------
__global__ __launch_bounds__(256) void ln_cast(const float* __restrict__ x,
                                               const float* __restrict__ w,
                                               const float* __restrict__ bb,
                                               u16* __restrict__ y) {
    int row = blockIdx.x;
    const float4 v = ((const float4*)(x + (size_t)row * D_MODEL))[threadIdx.x];
    float s  = v.x + v.y + v.z + v.w;
    float sq = v.x*v.x + v.y*v.y + v.z*v.z + v.w*v.w;
    #pragma unroll
    for (int o = 32; o > 0; o >>= 1) {
        s  += __shfl_down(s,  o, 64);
        sq += __shfl_down(sq, o, 64);
    }
    __shared__ float sh[8];
    int wv = threadIdx.x >> 6;
    if ((threadIdx.x & 63) == 0) { sh[wv] = s; sh[4 + wv] = sq; }
    __syncthreads();
    s  = sh[0] + sh[1] + sh[2] + sh[3];
    sq = sh[4] + sh[5] + sh[6] + sh[7];
    float mu  = s * (1.f / D_MODEL);
    float var = sq * (1.f / D_MODEL) - mu * mu;
    float inv = rsqrtf(var + 1e-5f);
    int c = threadIdx.x * 4;
    ushort4 o4;
    o4.x = f2bf((v.x - mu) * inv * w[c+0] + bb[c+0]);
    o4.y = f2bf((v.y - mu) * inv * w[c+1] + bb[c+1]);
    o4.z = f2bf((v.z - mu) * inv * w[c+2] + bb[c+2]);
    o4.w = f2bf((v.w - mu) * inv * w[c+3] + bb[c+3]);
    ((ushort4*)(y + (size_t)row * D_MODEL))[threadIdx.x] = o4;
}

// ================= 2-phase (T3-minimum) bf16 MFMA GEMM =================
// C[M,N] = A[M,K] * B[N,K]^T.  Waves: WM x WN, wave tile (BM/WM) x (BN/WN).
// Per kt: stage(next buf) -> ds_read cur -> setprio(1) MFMA setprio(0)
//         -> vmcnt(0) -> barrier.  ONE barrier per K-tile.  [m248v2: 666 TF
//         @256^2 K=1024 for this structure]
// XOR bank-swizzle via pre-swizzled global source + swizzled ds_read.
// EPI 0: split u/z (col<2048 -> u, else silu -> zs).  EPI 3: fp32 out+resid.
template<int EPI, int BM, int BN, int WM, int WN, int K, int NTN, int NWG>
__global__ __launch_bounds__(WM*WN*64) void gemm2ph(
    const u16* __restrict__ A, const u16* __restrict__ B,
    float* __restrict__ fo0, u16* __restrict__ bo0, u16* __restrict__ bo1,
    const float* __restrict__ e0)
{
    constexpr int T  = WM * WN * 64;
    constexpr int R  = T / 8;               // rows per staging issue
    constexpr int IA = BM * 64 / (T * 8);   // staging issues for A
    constexpr int IB = BN * 64 / (T * 8);
    constexpr int MR = BM / WM / 16;        // m-fragments per wave
    constexpr int NR = BN / WN / 16;
    constexpr int NKT = K / 64;

    __shared__ u16 lds[2][(BM + BN) * 64];

    const int tid = threadIdx.x, wid = tid >> 6, lane = tid & 63;
    const int wm = wid / WN, wn = wid % WN;
    const int lr = lane & 15;

    // bijective XCD swizzle (NWG % 8 == 0)
    const int nb = (blockIdx.x & 7) * (NWG >> 3) + (blockIdx.x >> 3);
    const int bm = (nb / NTN) * BM, bn = (nb % NTN) * BN;

    // staging addresses: row = tid/8 (+ i*R), source col chunk pre-swizzled
    const int srow = tid >> 3;
    const int scol = 8 * ((lane & 7) ^ ((tid >> 3) & 7));
    const u16* Asrc = A + (size_t)(bm + srow) * K + scol;
    const u16* Bsrc = B + (size_t)(bn + srow) * K + scol;
    const int dwave = wid * 512;

    auto stage = [&](int buf, int kt) {
        const u16* a = Asrc + kt * 64;
        #pragma unroll
        for (int i = 0; i < IA; ++i)
            gload16(a + (size_t)i * R * K, &lds[buf][i * T * 8 + dwave]);
        const u16* b = Bsrc + kt * 64;
        #pragma unroll
        for (int i = 0; i < IB; ++i)
            gload16(b + (size_t)i * R * K, &lds[buf][BM * 64 + i * T * 8 + dwave]);
    };

    // swizzled ds_read cols for k-slot s: chunk = (s*4 + lane>>4) ^ (row&7)
    const int col0 = ((0 + (lane >> 4)) ^ (lr & 7)) << 3;
    const int col1 = ((4 + (lane >> 4)) ^ (lr & 7)) << 3;

    f32x4 acc[MR][NR];
    #pragma unroll
    for (int m = 0; m < MR; ++m)
        #pragma unroll
        for (int n = 0; n < NR; ++n)
            #pragma unroll
            for (int r = 0; r < 4; ++r) acc[m][n][r] = 0.f;

    stage(0, 0);
    VMCNT0();
    __builtin_amdgcn_s_barrier();

    for (int kt = 0; kt < NKT; ++kt) {
        const int cb = kt & 1;
        if (kt + 1 < NKT) stage(cb ^ 1, kt + 1);

        bf16x8 af[MR][2], bq[NR][2];
        #pragma unroll
        for (int m = 0; m < MR; ++m) {
            const int row = wm * (BM / WM) + m * 16 + lr;
            af[m][0] = *(const bf16x8*)&lds[cb][row * 64 + col0];
            af[m][1] = *(const bf16x8*)&lds[cb][row * 64 + col1];
        }
        #pragma unroll
        for (int n = 0; n < NR; ++n) {
            const int row = wn * (BN / WN) + n * 16 + lr;
            bq[n][0] = *(const bf16x8*)&lds[cb][BM * 64 + row * 64 + col0];
            bq[n][1] = *(const bf16x8*)&lds[cb][BM * 64 + row * 64 + col1];
        }
        __builtin_amdgcn_s_setprio(1);
        #pragma unroll
        for (int s = 0; s < 2; ++s)
            #pragma unroll
            for (int m = 0; m < MR; ++m)
                #pragma unroll
                for (int n = 0; n < NR; ++n)
                    acc[m][n] = __builtin_amdgcn_mfma_f32_16x16x32_bf16(af[m][s], bq[n][s], acc[m][n], 0, 0, 0);
        __builtin_amdgcn_s_setprio(0);
        if (kt + 1 < NKT) {
            VMCNT0();
            __builtin_amdgcn_s_barrier();
        }
    }

    // epilogue
    const int cr0 = (lane >> 4) * 4;
    const int cc  = lr;
    #pragma unroll
    for (int m = 0; m < MR; ++m) {
        #pragma unroll
        for (int n = 0; n < NR; ++n) {
            #pragma unroll
            for (int r = 0; r < 4; ++r) {
                int row = bm + wm * (BM / WM) + m * 16 + cr0 + r;
                int col = bn + wn * (BN / WN) + n * 16 + cc;
                float v = acc[m][n][r];
                if (EPI == 0) {
                    if (col < D_INNER) {
                        bo0[(size_t)row * D_INNER + col] = f2bf(v);
                    } else {
                        float s = v / (1.f + __expf(-v));
                        bo1[(size_t)row * D_INNER + (col - D_INNER)] = f2bf(s);
                    }
                } else { // EPI == 3
                    fo0[(size_t)row * 1024 + col] = v + e0[(size_t)row * 1024 + col];
                }
            }
        }
    }
}

// ---------------- 128^2 prefetch-dbuf GEMM (small-N/small-K / split-K) ----------------
// EPI 1: split-K partial: fp32 fo0[row*96+col] (col<96)
// EPI 2: dt:  softplus(acc + e0[col]) -> bf16 bo0[row*2048+col]
template<int EPI>
static __device__ __forceinline__ void gemm_core(
    const u16* __restrict__ A, const u16* __restrict__ B,
    int bm, int bn, int kbeg, int klen, int lda,
    float* __restrict__ fo0, u16* __restrict__ bo0,
    const float* __restrict__ e0)
{
    __shared__ u16 As[2][128 * 64];
    __shared__ u16 Bs[2][128 * 64];
    const int tid  = threadIdx.x;
    const int wid  = tid >> 6, lane = tid & 63;
    const int wm   = (wid >> 1) * 64, wn = (wid & 1) * 64;
    const int lr   = lane & 15, lk = (lane >> 4) * 8;

    const u16* Ag = A + (size_t)(bm + 32*wid + (lane >> 3)) * lda + kbeg + (lane & 7) * 8;
    const u16* Bg = B + (size_t)(bn + 32*wid + (lane >> 3)) * lda + kbeg + (lane & 7) * 8;
    const int lbase = wid * 2048;

    f32x4 acc[4][4];
    #pragma unroll
    for (int m = 0; m < 4; ++m)
        #pragma unroll
        for (int n = 0; n < 4; ++n)
            #pragma unroll
            for (int r = 0; r < 4; ++r) acc[m][n][r] = 0.f;

    auto stage = [&](int buf, int k0) {
        #pragma unroll
        for (int i = 0; i < 4; ++i) {
            gload16(Ag + (size_t)(8*i) * lda + k0, &As[buf][lbase + i * 512]);
            gload16(Bg + (size_t)(8*i) * lda + k0, &Bs[buf][lbase + i * 512]);
        }
    };

    const int nt = klen >> 6;
    stage(0, 0);
    for (int t = 0; t < nt; ++t) {
        __syncthreads();
        if (t + 1 < nt) stage((t + 1) & 1, (t + 1) << 6);
        const int cb = t & 1;
        #pragma unroll
        for (int ks = 0; ks < 2; ++ks) {
            bf16x8 af[4], bfr[4];
            #pragma unroll
            for (int m = 0; m < 4; ++m)
                af[m] = *(const bf16x8*)&As[cb][(wm + m*16 + lr) * 64 + ks*32 + lk];
            #pragma unroll
            for (int n = 0; n < 4; ++n)
                bfr[n] = *(const bf16x8*)&Bs[cb][(wn + n*16 + lr) * 64 + ks*32 + lk];
            #pragma unroll
            for (int m = 0; m < 4; ++m)
                #pragma unroll
                for (int n = 0; n < 4; ++n)
                    acc[m][n] = __builtin_amdgcn_mfma_f32_16x16x32_bf16(af[m], bfr[n], acc[m][n], 0, 0, 0);
        }
    }

    const int cr0 = (lane >> 4) * 4;
    const int cc  = lane & 15;
    #pragma unroll
    for (int m = 0; m < 4; ++m) {
        #pragma unroll
        for (int n = 0; n < 4; ++n) {
            #pragma unroll
            for (int r = 0; r < 4; ++r) {
                int row = bm + wm + m*16 + cr0 + r;
                int col = bn + wn + n*16 + cc;
                float v = acc[m][n][r];
                if (EPI == 1) {
                    if (col < 96) fo0[(size_t)row * 96 + col] = v;
                } else if (EPI == 2) {
                    float t2 = v + e0[col];
                    float sp = fmaxf(t2, 0.f) + __logf(1.f + __expf(-fabsf(t2)));
                    bo0[(size_t)row * D_INNER + col] = f2bf(sp);
                }
            }
        }
    }
}

// x_proj split-K: grid 32 m-tiles x 8 splits; partial fp32 -> psum[s][4096][96]
__global__ __launch_bounds__(256) void gemm_xp(const u16* __restrict__ A, const u16* __restrict__ B,
                                               float* __restrict__ psum) {
    int bm = blockIdx.x >> 3;
    int s  = blockIdx.x & 7;
    gemm_core<1>(A, B, bm * 128, 0, s * 256, 256, 2048,
                 psum + (size_t)s * 4096 * 96, nullptr, nullptr);
}
// reduce 8 partials -> xdbl fp32 + dtin bf16
__global__ __launch_bounds__(256) void xp_reduce(const float* __restrict__ psum,
                                                 float* __restrict__ xdbl,
                                                 u16* __restrict__ dtinb) {
    int t = blockIdx.x * 256 + threadIdx.x;      // 4096*24 = 98304
    int row = t / 24, c4 = (t - row * 24) * 4;
    float4 s = {0.f, 0.f, 0.f, 0.f};
    #pragma unroll
    for (int k = 0; k < 8; ++k) {
        float4 v = *(const float4*)&psum[(size_t)k * 4096 * 96 + (size_t)row * 96 + c4];
        s.x += v.x; s.y += v.y; s.z += v.z; s.w += v.w;
    }
    *(float4*)&xdbl[(size_t)row * 96 + c4] = s;
    if (c4 < 64) {
        ushort4 o4;
        o4.x = f2bf(s.x); o4.y = f2bf(s.y); o4.z = f2bf(s.z); o4.w = f2bf(s.w);
        *(ushort4*)&dtinb[(size_t)row * 64 + c4] = o4;
    }
}

__global__ __launch_bounds__(256) void gemm_dt(const u16* __restrict__ A, const u16* __restrict__ B,
                                               u16* __restrict__ dtb, const float* __restrict__ bias) {
    int q = 512 >> 3;
    int nb = (blockIdx.x & 7) * q + (blockIdx.x >> 3);
    int bm = nb >> 4, bn = nb & 15;
    gemm_core<2>(A, B, bm * 128, bn * 128, 0, 64, 64, nullptr, dtb, bias);
}

// ---------------- depthwise causal conv(4) + bias + silu (8 d's / thread) ----------------
__global__ __launch_bounds__(256) void conv_silu(const u16* __restrict__ u,
                                                 const float* __restrict__ cw,
                                                 const float* __restrict__ cb,
                                                 u16* __restrict__ uc) {
    int tok = blockIdx.x;                        // 0..4095
    int d0  = threadIdx.x * 8;                   // 0..2040
    int t   = tok & (SEQ - 1);
    float acc[8];
    {
        float4 b0 = *(const float4*)&cb[d0];
        float4 b1 = *(const float4*)&cb[d0 + 4];
        acc[0]=b0.x; acc[1]=b0.y; acc[2]=b0.z; acc[3]=b0.w;
        acc[4]=b1.x; acc[5]=b1.y; acc[6]=b1.z; acc[7]=b1.w;
    }
    float4 c4[8];
    #pragma unroll
    for (int e = 0; e < 8; ++e) c4[e] = *(const float4*)&cw[(d0 + e) * 4];
    #pragma unroll
    for (int j = 0; j < 4; ++j) {
        int tt = t - 3 + j;
        if (tt < 0) continue;                    // uniform per block
        u16x8 uv = *(const u16x8*)&u[(size_t)(tok - 3 + j) * D_INNER + d0];
        const float* cj = (const float*)c4;
        #pragma unroll
        for (int e = 0; e < 8; ++e)
            acc[e] += bf2f(uv[e]) * cj[e * 4 + j];
    }
    u16x8 o;
    #pragma unroll
    for (int e = 0; e < 8; ++e) {
        float s = acc[e] / (1.f + __expf(-acc[e]));
        ((u16*)&o)[e] = f2bf(s);
    }
    *(u16x8*)&uc[(size_t)tok * D_INNER + d0] = o;
}

// ---------------- scan pass 1: per-chunk local end state + sum(dt) ----------------
__global__ __launch_bounds__(256) void scan1(const u16* __restrict__ dtb,
                                             const u16* __restrict__ uc,
                                             const float* __restrict__ xdbl,
                                             const float* __restrict__ A_log,
                                             float* __restrict__ hend,
                                             float* __restrict__ sdt_out) {
    int d = blockIdx.x * 256 + threadIdx.x;
    int c = blockIdx.y, b = blockIdx.z;
    float a2[NSTATE];
    #pragma unroll
    for (int n = 0; n < NSTATE; ++n)
        a2[n] = -__expf(A_log[d * NSTATE + n]) * LOG2E;
    float h[NSTATE];
    #pragma unroll
    for (int n = 0; n < NSTATE; ++n) h[n] = 0.f;
    float sdt = 0.f;
    int tok0 = b * SEQ + c * CHUNK;
    for (int t = 0; t < CHUNK; ++t) {
        int tok = tok0 + t;
        float dtv = bf2f(dtb[(size_t)tok * D_INNER + d]);
        float uv  = bf2f(uc[(size_t)tok * D_INNER + d]);
        float dtu = dtv * uv;
        const float4* Bp = (const float4*)(xdbl + (size_t)tok * 96 + 64);
        float4 B0 = Bp[0], B1 = Bp[1], B2 = Bp[2], B3 = Bp[3];
        float Bv[NSTATE] = {B0.x,B0.y,B0.z,B0.w, B1.x,B1.y,B1.z,B1.w,
                            B2.x,B2.y,B2.z,B2.w, B3.x,B3.y,B3.z,B3.w};
        sdt += dtv;
        #pragma unroll
        for (int n = 0; n < NSTATE; ++n) {
            float da = exp2f(a2[n] * dtv);
            h[n] = fmaf(da, h[n], dtu * Bv[n]);
        }
    }
    sdt_out[(size_t)(b * NCH + c) * D_INNER + d] = sdt;
    #pragma unroll
    for (int n = 0; n < NSTATE; ++n)
        hend[((size_t)(b * NCH + c) * NSTATE + n) * D_INNER + d] = h[n];
}

// ---------------- inter-chunk carry scan (in-place: hend -> carry-in) ----------------
__global__ __launch_bounds__(256) void scan_carry(float* __restrict__ hend,
                                                  const float* __restrict__ sdt,
                                                  const float* __restrict__ A_log) {
    int g = blockIdx.x * 256 + threadIdx.x;     // 65536
    int d = g & (D_INNER - 1);
    int n = (g >> 11) & (NSTATE - 1);
    int b = g >> 15;
    float a2 = -__expf(A_log[d * NSTATE + n]) * LOG2E;
    float H = 0.f;
    for (int c = 0; c < NCH; ++c) {
        size_t off = ((size_t)(b * NCH + c) * NSTATE + n) * D_INNER + d;
        float v = hend[off];
        float p = exp2f(a2 * sdt[(size_t)(b * NCH + c) * D_INNER + d]);
        hend[off] = H;                 // carry-in for chunk c
        H = fmaf(p, H, v);
    }
}

// ---------------- scan pass 2: full recurrence + Dskip + gate -> ys bf16 ----------------
__global__ __launch_bounds__(256) void scan2(const u16* __restrict__ dtb,
                                             const u16* __restrict__ uc,
                                             const float* __restrict__ xdbl,
                                             const float* __restrict__ A_log,
                                             const float* __restrict__ hin,
                                             const float* __restrict__ Dskip,
                                             const u16* __restrict__ zs,
                                             u16* __restrict__ ys) {
    int d = blockIdx.x * 256 + threadIdx.x;
    int c = blockIdx.y, b = blockIdx.z;
    float a2[NSTATE];
    #pragma unroll
    for (int n = 0; n < NSTATE; ++n)
        a2[n] = -__expf(A_log[d * NSTATE + n]) * LOG2E;
    float h[NSTATE];
    #pragma unroll
    for (int n = 0; n < NSTATE; ++n)
        h[n] = hin[((size_t)(b * NCH + c) * NSTATE + n) * D_INNER + d];
    float Dv = Dskip[d];
    int tok0 = b * SEQ + c * CHUNK;
    for (int t = 0; t < CHUNK; ++t) {
        int tok = tok0 + t;
        float dtv = bf2f(dtb[(size_t)tok * D_INNER + d]);
        float uv  = bf2f(uc[(size_t)tok * D_INNER + d]);
        float dtu = dtv * uv;
        const float4* Bp = (const float4*)(xdbl + (size_t)tok * 96 + 64);
        float4 B0 = Bp[0], B1 = Bp[1], B2 = Bp[2], B3 = Bp[3];
        const float4* Cp = (const float4*)(xdbl + (size_t)tok * 96 + 80);
        float4 C0 = Cp[0], C1 = Cp[1], C2 = Cp[2], C3 = Cp[3];
        float Bv[NSTATE] = {B0.x,B0.y,B0.z,B0.w, B1.x,B1.y,B1.z,B1.w,
                            B2.x,B2.y,B2.z,B2.w, B3.x,B3.y,B3.z,B3.w};
        float Cv[NSTATE] = {C0.x,C0.y,C0.z,C0.w, C1.x,C1.y,C1.z,C1.w,
                            C2.x,C2.y,C2.z,C2.w, C3.x,C3.y,C3.z,C3.w};
        float y = 0.f;
        #pragma unroll
        for (int n = 0; n < NSTATE; ++n) {
            float da = exp2f(a2[n] * dtv);
            h[n] = fmaf(da, h[n], dtu * Bv[n]);
            y = fmaf(h[n], Cv[n], y);
        }
        float g = bf2f(zs[(size_t)tok * D_INNER + d]);
        ys[(size_t)tok * D_INNER + d] = f2bf((y + uv * Dv) * g);
    }
}

// ---------------- host launcher ----------------
extern "C" void kernel_launch(void* const* d_in, const int* in_sizes, int n_in,
                              void* d_out, int out_size, void* d_ws, size_t ws_size,
                              hipStream_t stream) {
    const float* x        = (const float*)d_in[0];
    const float* ln_w     = (const float*)d_in[1];
    const float* ln_b     = (const float*)d_in[2];
    const float* in_projw = (const float*)d_in[3];
    const float* conv_w   = (const float*)d_in[4];
    const float* conv_b   = (const float*)d_in[5];
    const float* x_projw  = (const float*)d_in[6];
    const float* dt_projw = (const float*)d_in[7];
    const float* dt_projb = (const float*)d_in[8];
    const float* A_log    = (const float*)d_in[9];
    const float* Dskip    = (const float*)d_in[10];
    const float* out_projw= (const float*)d_in[11];
    float* out = (float*)d_out;

    uint8_t* w = (uint8_t*)d_ws;
    size_t off = 0;
    auto alloc = [&](size_t bytes) { uint8_t* p = w + off; off += (bytes + 255) & ~(size_t)255; return p; };

    u16* w1b   = (u16*)alloc((size_t)N_W1 * 2);
    u16* woutb = (u16*)alloc((size_t)N_WO * 2);
    u16* xpb   = (u16*)alloc((size_t)N_XPP * 2);   // padded to 128 rows
    u16* dtwb  = (u16*)alloc((size_t)N_DTW * 2);
    u16* y_bf  = (u16*)alloc((size_t)NTOK * 1024 * 2);
    u16* u_bf  = (u16*)alloc((size_t)NTOK * 2048 * 2);   // reused as ys_bf after conv
    u16* zs_bf = (u16*)alloc((size_t)NTOK * 2048 * 2);
    u16* uc_bf = (u16*)alloc((size_t)NTOK * 2048 * 2);
    float* xdbl  = (float*)alloc((size_t)NTOK * 96 * 4);
    u16*   dtinb = (u16*)alloc((size_t)NTOK * 64 * 2);
    u16*   dt_bf = (u16*)alloc((size_t)NTOK * 2048 * 2);
    float* sdt   = (float*)alloc((size_t)BATCH * NCH * 2048 * 4);
    float* hend  = (float*)alloc((size_t)BATCH * NCH * NSTATE * 2048 * 4);
    float* psum  = (float*)alloc((size_t)8 * 4096 * 96 * 4);
    u16* ys_bf = u_bf;
    (void)ws_size; (void)n_in; (void)in_sizes; (void)out_size;

    // fused weight casts (+ x_proj zero-pad)
    cast_weights<<<2048, 256, 0, stream>>>(in_projw, out_projw, x_projw, dt_projw,
                                           w1b, woutb, xpb, dtwb);

    // LayerNorm -> bf16
    ln_cast<<<NTOK, 256, 0, stream>>>(x, ln_w, ln_b, y_bf);

    // in_proj: [4096,1024] x [4096,1024]^T -> split u / silu(z)   (2ph 256^2)
    gemm2ph<0, 256, 256, 2, 4, 1024, 16, 256><<<256, 512, 0, stream>>>(
        y_bf, w1b, nullptr, u_bf, zs_bf, nullptr);

    // conv + silu
    conv_silu<<<NTOK, 256, 0, stream>>>(u_bf, conv_w, conv_b, uc_bf);

    // x_proj split-K: [4096,2048] x [128(pad),2048]^T -> 8 partials -> reduce
    gemm_xp<<<256, 256, 0, stream>>>(uc_bf, xpb, psum);
    xp_reduce<<<384, 256, 0, stream>>>(psum, xdbl, dtinb);

    // dt_proj + softplus -> bf16: [4096,64] x [2048,64]^T
    gemm_dt<<<512, 256, 0, stream>>>(dtinb, dtwb, dt_bf, dt_projb);

    // chunked selective scan
    scan1<<<dim3(8, NCH, BATCH), 256, 0, stream>>>(dt_bf, uc_bf, xdbl, A_log, hend, sdt);
    scan_carry<<<256, 256, 0, stream>>>(hend, sdt, A_log);
    scan2<<<dim3(8, NCH, BATCH), 256, 0, stream>>>(dt_bf, uc_bf, xdbl, A_log, hend, Dskip, zs_bf, ys_bf);

    // out_proj + residual   (2ph 128x64, grid 512 = 2 blocks/CU)
    gemm2ph<3, 128, 64, 2, 2, 2048, 16, 512><<<512, 256, 0, stream>>>(
        ys_bf, woutb, out, nullptr, nullptr, x);
}